// Round 5
// baseline (3088.196 us; speedup 1.0000x reference)
//
#include <hip/hip_runtime.h>
#include <stdint.h>

#define B_   4
#define N_   4096
#define DIM_ 512
#define H_   8
#define DH_  64
#define E3_  1536
#define M_   (B_*N_)   // 16384

__device__ inline float bf2f(unsigned short u){ return __uint_as_float(((unsigned)u)<<16); }

// ---------------- format detection ----------------
// flags[0]: x fp32?  flags[1]: W/bias fp32?  flags[2]: mask 0=i32,1=f32,2=bf16,3=u8
__global__ void detect_fmt(const unsigned int* __restrict__ xw,
                           const unsigned int* __restrict__ ww,
                           const unsigned int* __restrict__ mw,
                           int* __restrict__ flags)
{
  __shared__ int cnt[2];
  __shared__ int ok[3];
  if (threadIdx.x < 2) cnt[threadIdx.x] = 0;
  if (threadIdx.x < 3) ok[threadIdx.x] = 1;
  __syncthreads();
  int hx = 0, hw = 0;
  for (int i = threadIdx.x; i < 1024; i += 256) {
    if (((xw[i] >> 7) & 0xFFu) > 140u) hx++;   // fp32 mantissa bits ~uniform; bf16 exp of N(0,1) never >140
    if (((ww[i] >> 7) & 0xFFu) > 140u) hw++;
  }
  int okInt = 1, okF32 = 1, okBf = 1;
  for (int i = threadIdx.x; i < 4096; i += 256) {   // 16 KB: valid under every mask hypothesis
    unsigned w = mw[i];
    if (w > 1u) okInt = 0;
    if (w != 0u && w != 0x3F800000u) okF32 = 0;
    unsigned short a = (unsigned short)(w & 0xFFFFu), b = (unsigned short)(w >> 16);
    if (!((a == 0 || a == 0x3F80u) && (b == 0 || b == 0x3F80u))) okBf = 0;
  }
  atomicAdd(&cnt[0], hx);
  atomicAdd(&cnt[1], hw);
  if (!okInt) atomicAnd(&ok[0], 0);
  if (!okF32) atomicAnd(&ok[1], 0);
  if (!okBf)  atomicAnd(&ok[2], 0);
  __syncthreads();
  if (threadIdx.x == 0) {
    flags[0] = cnt[0] > 64 ? 1 : 0;
    flags[1] = cnt[1] > 64 ? 1 : 0;
    flags[2] = ok[0] ? 0 : (ok[1] ? 1 : (ok[2] ? 2 : 3));
  }
}

__device__ inline bool mask_at(const void* m, int flag, int idx){
  if (flag == 0) return ((const int*)m)[idx] != 0;
  if (flag == 1) return ((const float*)m)[idx] != 0.f;
  if (flag == 2) return ((const unsigned short*)m)[idx] != 0;
  return ((const unsigned char*)m)[idx] != 0;
}

__device__ inline float gread(const void* p, int f32, size_t i){
  return f32 ? ((const float*)p)[i] : bf2f(((const unsigned short*)p)[i]);
}

// stage 16 x-rows (tokens n0..n0+15) x 512 c into xa, coalesced float4 on fp32 path
__device__ inline void stage_x(float (*xa)[516], const void* x, int xf,
                               int brow0, int t)
{
  if (xf) {
    const float* xp = (const float*)x;
    #pragma unroll
    for (int s = 0; s < 8; ++s) {
      int row = (t >> 7) + 2 * s;          // 2 rows per pass
      int col = (t & 127) * 4;
      float4 v = *(const float4*)(xp + ((size_t)(brow0 + row)) * DIM_ + col);
      *(float4*)&xa[row][col] = v;
    }
  } else {
    const unsigned short* xp = (const unsigned short*)x;
    #pragma unroll
    for (int s = 0; s < 8; ++s) {
      int row = (t >> 7) + 2 * s;
      int col = (t & 127) * 4;
      const unsigned short* pp = xp + ((size_t)(brow0 + row)) * DIM_ + col;
      #pragma unroll
      for (int j = 0; j < 4; ++j) xa[row][col + j] = bf2f(pp[j]);
    }
  }
}

// ---------------- pass 1: kv[bh][d][e] = sum_n exp(k[n,d])*v[n,e]; denom[bh][d] ----------------
// Fully fused: k,v computed on the fly from x @ W (+bias). No qkv materialization.
__global__ __launch_bounds__(256)
void kv_pass(const void* __restrict__ x, const void* __restrict__ w,
             const void* __restrict__ bias, const void* __restrict__ mask,
             const int* __restrict__ flags,
             float* __restrict__ kvbuf, float* __restrict__ denom)
{
  const int chunk = blockIdx.x;   // 0..15
  const int bh    = blockIdx.y;   // 0..31
  const int b = bh >> 3, h = bh & 7;
  const int t = threadIdx.x;
  const int xf = flags[0], wf = flags[1], mf = flags[2];

  __shared__ float xa[16][516];    // 16 tokens x 512 c, pad 4
  __shared__ float Wb[64][130];    // 64 c-rows x (64 k-cols | 64 v-cols), pad 2
  float* ekb = &Wb[0][0];          // overlay after last Wb use: [16][65]
  float* vvb = &Wb[0][0] + 16 * 65;

  const int tok  = t >> 4;        // 0..15 (GEMM ownership)
  const int d0   = (t & 15) * 4;  // 4 k-dims + 4 v-dims
  const int down = t >> 2;        // 0..63 (outer-product ownership)
  const int e0   = (t & 3) * 16;

  float acc[16];
  #pragma unroll
  for (int i = 0; i < 16; ++i) acc[i] = 0.f;
  float dsum = 0.f;

  for (int g = 0; g < 16; ++g) {
    const int n0 = chunk * 256 + g * 16;
    __syncthreads();   // prev group's ekb/vvb + xa reads complete
    stage_x(xa, x, xf, b * N_ + n0, t);

    float kreg[4] = {0.f,0.f,0.f,0.f}, vreg[4] = {0.f,0.f,0.f,0.f};
    for (int cc = 0; cc < 8; ++cc) {
      __syncthreads();   // xa staged (cc=0) / prev MAC's Wb reads done
      {  // stage W chunk: 64 c-rows x 128 cols (coalesced: lane->col, loop over rows)
        int c0  = (t >> 7) * 32;
        int col = t & 127;
        int wc  = (col < 64) ? (512 + h * DH_ + col) : (1024 + h * DH_ + (col - 64));
        #pragma unroll 8
        for (int j = 0; j < 32; ++j)
          Wb[c0 + j][col] = gread(w, wf, (size_t)(cc * 64 + c0 + j) * E3_ + wc);
      }
      __syncthreads();
      #pragma unroll 4
      for (int c = 0; c < 64; ++c) {
        float xv = xa[tok][cc * 64 + c];
        #pragma unroll
        for (int j = 0; j < 4; ++j) {
          kreg[j] += xv * Wb[c][d0 + j];
          vreg[j] += xv * Wb[c][64 + d0 + j];
        }
      }
    }
    bool mk = mask_at(mask, mf, b * N_ + n0 + tok);
    __syncthreads();   // last Wb reads done -> safe to overlay ekb/vvb
    #pragma unroll
    for (int j = 0; j < 4; ++j) {
      float kvl = kreg[j] + gread(bias, wf, 512  + h * DH_ + d0 + j);
      float vvl = vreg[j] + gread(bias, wf, 1024 + h * DH_ + d0 + j);
      ekb[tok * 65 + d0 + j] = mk ? __expf(kvl) : 0.f;
      vvb[tok * 65 + d0 + j] = mk ? vvl : 0.f;
    }
    __syncthreads();
    #pragma unroll 4
    for (int nn = 0; nn < 16; ++nn) {
      float ekd = ekb[nn * 65 + down];
      if (e0 == 0) dsum += ekd;
      #pragma unroll
      for (int i = 0; i < 16; ++i) acc[i] += ekd * vvb[nn * 65 + e0 + i];
    }
  }
  float* kvp = kvbuf + (size_t)bh * 4096 + down * 64 + e0;
  #pragma unroll
  for (int i = 0; i < 16; ++i) atomicAdd(&kvp[i], acc[i]);
  if (e0 == 0) atomicAdd(&denom[bh * 64 + down], dsum);
}

// ---------------- pass 2: q on the fly, q-softmax over d, out = kv_norm^T q ----------------
__global__ __launch_bounds__(256)
void out_pass(const void* __restrict__ x, const void* __restrict__ w,
              const void* __restrict__ bias, const int* __restrict__ flags,
              const float* __restrict__ kvbuf, const float* __restrict__ denom,
              float* __restrict__ out)
{
  const int chunk = blockIdx.x;   // 0..15
  const int bh    = blockIdx.y;   // 0..31
  const int b = bh >> 3, h = bh & 7;
  const int t = threadIdx.x;
  const int xf = flags[0], wf = flags[1];

  __shared__ float xa[16][516];
  __shared__ float Wq[64][66];     // 64 c-rows x 64 q-cols, pad 2
  __shared__ float kvn[64][68];    // normalized kv
  float* qsm = &Wq[0][0];          // overlay: [16][65]

  for (int i = t; i < 4096; i += 256) {
    int d = i >> 6, e = i & 63;
    kvn[d][e] = kvbuf[(size_t)bh * 4096 + i] / denom[bh * 64 + d];
  }

  const int tok = t >> 4;         // 0..15
  const int p   = t & 15;
  const int d0  = p * 4;

  for (int g = 0; g < 16; ++g) {
    const int n0 = chunk * 256 + g * 16;
    __syncthreads();   // covers kvn (g=0) and prev-group xa/qsm reads
    stage_x(xa, x, xf, b * N_ + n0, t);

    float qreg[4] = {0.f,0.f,0.f,0.f};
    for (int cc = 0; cc < 8; ++cc) {
      __syncthreads();
      {  // stage Wq chunk: 64 rows x 64 cols (coalesced: lane->col, loop over rows)
        int col = t & 63;
        int c0  = (t >> 6) * 16;
        #pragma unroll 8
        for (int j = 0; j < 16; ++j)
          Wq[c0 + j][col] = gread(w, wf, (size_t)(cc * 64 + c0 + j) * E3_ + h * DH_ + col);
      }
      __syncthreads();
      #pragma unroll 4
      for (int c = 0; c < 64; ++c) {
        float xv = xa[tok][cc * 64 + c];
        #pragma unroll
        for (int j = 0; j < 4; ++j) qreg[j] += xv * Wq[c][d0 + j];
      }
    }
    #pragma unroll
    for (int j = 0; j < 4; ++j) qreg[j] += gread(bias, wf, h * DH_ + d0 + j);
    // q-softmax across this token's 16 lanes x 4 regs (16-lane groups are wave-aligned)
    float mx = fmaxf(fmaxf(qreg[0], qreg[1]), fmaxf(qreg[2], qreg[3]));
    #pragma unroll
    for (int o = 1; o < 16; o <<= 1) mx = fmaxf(mx, __shfl_xor(mx, o, 16));
    float s = 0.f;
    #pragma unroll
    for (int j = 0; j < 4; ++j) { qreg[j] = __expf(qreg[j] - mx); s += qreg[j]; }
    #pragma unroll
    for (int o = 1; o < 16; o <<= 1) s += __shfl_xor(s, o, 16);
    float inv = 1.f / s;
    __syncthreads();   // Wq reads done -> overlay qsm
    #pragma unroll
    for (int j = 0; j < 4; ++j) qsm[tok * 65 + d0 + j] = qreg[j] * inv;
    __syncthreads();
    {  // out[n0+tok][h*64 + e0..e0+4] = sum_d qsm[tok][d] * kvn[d][e]
      int e0 = p * 4;
      float ov[4] = {0.f,0.f,0.f,0.f};
      #pragma unroll 4
      for (int d = 0; d < 64; ++d) {
        float qd = qsm[tok * 65 + d];
        #pragma unroll
        for (int j = 0; j < 4; ++j) ov[j] += qd * kvn[d][e0 + j];
      }
      size_t ob = ((size_t)(b * N_ + n0 + tok)) * DIM_ + h * DH_ + e0;
      #pragma unroll
      for (int j = 0; j < 4; ++j) out[ob + j] = ov[j];
    }
  }
}

extern "C" void kernel_launch(void* const* d_in, const int* in_sizes, int n_in,
                              void* d_out, int out_size, void* d_ws, size_t ws_size,
                              hipStream_t stream)
{
  const void* x    = d_in[0];
  const void* mask = d_in[1];
  const void* w    = d_in[2];
  const void* bias = d_in[3];
  float* out = (float*)d_out;   // reference output dtype is float32

  // workspace: flags (16 B, padded to 256) + kvbuf (32*64*64 f32 = 512 KB) + denom (8 KB)
  char* ws = (char*)d_ws;
  int*   flags = (int*)ws;
  float* kvbuf = (float*)(ws + 256);
  float* denom = (float*)(ws + 256 + 32 * 4096 * 4);

  hipMemsetAsync(kvbuf, 0, 32 * 4096 * 4 + 32 * 64 * 4, stream);
  detect_fmt<<<1, 256, 0, stream>>>((const unsigned int*)x, (const unsigned int*)w,
                                    (const unsigned int*)mask, flags);

  dim3 grid(16, 32);   // (token-chunk, bh)
  kv_pass <<<grid, 256, 0, stream>>>(x, w, bias, mask, flags, kvbuf, denom);
  out_pass<<<grid, 256, 0, stream>>>(x, w, bias, flags, kvbuf, denom, out);
}

// Round 6
// 387.020 us; speedup vs baseline: 7.9794x; 7.9794x over previous
//
#include <hip/hip_runtime.h>
#include <stdint.h>

#define B_   4
#define N_   4096
#define DIM_ 512
#define H_   8
#define DH_  64
#define E3_  1536
#define M_   (B_*N_)   // 16384

typedef __attribute__((ext_vector_type(8))) __bf16 bf16x8;
typedef __attribute__((ext_vector_type(8))) unsigned short ushort8;
typedef __attribute__((ext_vector_type(4))) float f32x4;

__device__ inline float bf2f(unsigned short u){ return __uint_as_float(((unsigned)u)<<16); }
__device__ inline unsigned short f2bf(float f){
  unsigned u = __float_as_uint(f);
  u += 0x7FFFu + ((u>>16)&1u);   // RNE
  return (unsigned short)(u>>16);
}
__device__ inline float ldst(const float* p){ return *p; }
__device__ inline float ldst(const unsigned short* p){ return bf2f(*p); }
__device__ inline void stst(float* p, float v){ *p = v; }
__device__ inline void stst(unsigned short* p, float v){ *p = f2bf(v); }

// ---------------- format detection ----------------
// flags[0]: x fp32?  flags[1]: W/bias fp32?  flags[2]: mask 0=i32,1=f32,2=bf16,3=u8
__global__ void detect_fmt(const unsigned int* __restrict__ xw,
                           const unsigned int* __restrict__ ww,
                           const unsigned int* __restrict__ mw,
                           int* __restrict__ flags)
{
  __shared__ int cnt[2];
  __shared__ int ok[3];
  if (threadIdx.x < 2) cnt[threadIdx.x] = 0;
  if (threadIdx.x < 3) ok[threadIdx.x] = 1;
  __syncthreads();
  int hx = 0, hw = 0;
  for (int i = threadIdx.x; i < 1024; i += 256) {
    if (((xw[i] >> 7) & 0xFFu) > 140u) hx++;
    if (((ww[i] >> 7) & 0xFFu) > 140u) hw++;
  }
  int okInt = 1, okF32 = 1, okBf = 1;
  for (int i = threadIdx.x; i < 4096; i += 256) {
    unsigned w = mw[i];
    if (w > 1u) okInt = 0;
    if (w != 0u && w != 0x3F800000u) okF32 = 0;
    unsigned short a = (unsigned short)(w & 0xFFFFu), b = (unsigned short)(w >> 16);
    if (!((a == 0 || a == 0x3F80u) && (b == 0 || b == 0x3F80u))) okBf = 0;
  }
  atomicAdd(&cnt[0], hx);
  atomicAdd(&cnt[1], hw);
  if (!okInt) atomicAnd(&ok[0], 0);
  if (!okF32) atomicAnd(&ok[1], 0);
  if (!okBf)  atomicAnd(&ok[2], 0);
  __syncthreads();
  if (threadIdx.x == 0) {
    flags[0] = cnt[0] > 64 ? 1 : 0;
    flags[1] = cnt[1] > 64 ? 1 : 0;
    flags[2] = ok[0] ? 0 : (ok[1] ? 1 : (ok[2] ? 2 : 3));
  }
}

__device__ inline bool mask_at(const void* m, int flag, int idx){
  if (flag == 0) return ((const int*)m)[idx] != 0;
  if (flag == 1) return ((const float*)m)[idx] != 0.f;
  if (flag == 2) return ((const unsigned short*)m)[idx] != 0;
  return ((const unsigned char*)m)[idx] != 0;
}
__device__ inline float gread(const void* p, int f32, size_t i){
  return f32 ? ((const float*)p)[i] : bf2f(((const unsigned short*)p)[i]);
}

// ---------------- convert x -> bf16 ----------------
__global__ __launch_bounds__(256)
void conv_x(const void* __restrict__ src, unsigned short* __restrict__ dst,
            const int* __restrict__ flags)
{
  const int f = flags[0];
  size_t i = ((size_t)blockIdx.x * 256 + threadIdx.x) * 4;
  #pragma unroll
  for (int j = 0; j < 4; ++j) dst[i + j] = f2bf(gread(src, f, i + j));
}

// ---------------- convert + transpose W: wbT[n][k] = W[k][n] ----------------
__global__ __launch_bounds__(256)
void conv_wT(const void* __restrict__ w, unsigned short* __restrict__ wbT,
             const int* __restrict__ flags)
{
  const int f = flags[1];
  __shared__ unsigned short ts[64][66];
  const int n0 = blockIdx.x * 64;   // 24 tiles
  const int k0 = blockIdx.y * 64;   // 8 tiles
  const int t = threadIdx.x;
  const int c = t & 63;
  #pragma unroll
  for (int p = 0; p < 16; ++p) {
    int r = (t >> 6) * 16 + p;
    ts[r][c] = f2bf(gread(w, f, (size_t)(k0 + r) * E3_ + n0 + c));
  }
  __syncthreads();
  #pragma unroll
  for (int p = 0; p < 16; ++p) {
    int nrow = (t >> 6) * 16 + p;
    wbT[(size_t)(n0 + nrow) * DIM_ + k0 + c] = ts[c][nrow];
  }
}

// ---------------- QKV GEMM (MFMA): qkv = x @ W + b ----------------
// 128x128 tile, BK=32, 4 waves x (4x4) 16x16x32 fragments.
// Fragment layout (HW-confirmed via round-3 probe): A lane l: A[l&15][quad*8+j];
// B lane l: B[quad*8+j][l&15]; C/D lane l reg r: C[quad*4+r][l&15].
template<typename ST>
__global__ __launch_bounds__(256)
void qkv_gemm(const unsigned short* __restrict__ xb,   // M x 512 bf16
              const unsigned short* __restrict__ wbT,  // 1536 x 512 bf16 (W^T)
              const void* __restrict__ bias, const int* __restrict__ flags,
              ST* __restrict__ qkv)                    // M x 1536
{
  const int wf = flags[1];
  __shared__ alignas(16) unsigned short As[4][128][8];  // [k>>3][m][k&7]
  __shared__ alignas(16) unsigned short Bs[4][128][8];  // [k>>3][n][k&7]
  const int t = threadIdx.x;
  const int lane = t & 63, wv = t >> 6;
  const int quad = lane >> 4, l15 = lane & 15;
  const int m0 = blockIdx.y * 128, n0 = blockIdx.x * 128;
  const int mw = (wv & 1) * 64, nw = (wv >> 1) * 64;

  f32x4 acc[4][4];
  #pragma unroll
  for (int i = 0; i < 4; ++i)
    #pragma unroll
    for (int j = 0; j < 4; ++j) acc[i][j] = (f32x4){0.f,0.f,0.f,0.f};

  const int srow = t >> 1, sks = (t & 1) * 16;
  for (int kk = 0; kk < DIM_; kk += 32) {
    __syncthreads();
    {  // stage A and B tiles (coalesced b128 global, conflict-free b128 LDS)
      const ushort8* srcA = (const ushort8*)(xb + (size_t)(m0 + srow) * DIM_ + kk + sks);
      *(ushort8*)&As[(sks >> 3) + 0][srow][0] = srcA[0];
      *(ushort8*)&As[(sks >> 3) + 1][srow][0] = srcA[1];
      const ushort8* srcB = (const ushort8*)(wbT + (size_t)(n0 + srow) * DIM_ + kk + sks);
      *(ushort8*)&Bs[(sks >> 3) + 0][srow][0] = srcB[0];
      *(ushort8*)&Bs[(sks >> 3) + 1][srow][0] = srcB[1];
    }
    __syncthreads();
    ushort8 af[4], bfr[4];
    #pragma unroll
    for (int i = 0; i < 4; ++i) {
      af[i]  = *(const ushort8*)&As[quad][mw + i * 16 + l15][0];
      bfr[i] = *(const ushort8*)&Bs[quad][nw + i * 16 + l15][0];
    }
    #pragma unroll
    for (int i = 0; i < 4; ++i)
      #pragma unroll
      for (int j = 0; j < 4; ++j)
        acc[i][j] = __builtin_amdgcn_mfma_f32_16x16x32_bf16(
            __builtin_bit_cast(bf16x8, af[i]), __builtin_bit_cast(bf16x8, bfr[j]),
            acc[i][j], 0, 0, 0);
  }
  #pragma unroll
  for (int j = 0; j < 4; ++j) {
    int col = n0 + nw + j * 16 + l15;
    float bv = gread(bias, wf, col);
    #pragma unroll
    for (int i = 0; i < 4; ++i) {
      #pragma unroll
      for (int r = 0; r < 4; ++r) {
        int row = m0 + mw + i * 16 + quad * 4 + r;
        stst(&qkv[(size_t)row * E3_ + col], acc[i][j][r] + bv);
      }
    }
  }
}

// ---------------- kv accumulation from materialized k,v ----------------
template<typename ST>
__global__ __launch_bounds__(256)
void kv_accum(const ST* __restrict__ qkv, const void* __restrict__ mask,
              const int* __restrict__ flags,
              float* __restrict__ kvbuf, float* __restrict__ denom)
{
  const int chunk = blockIdx.x;   // 0..15
  const int bh    = blockIdx.y;   // 0..31
  const int b = bh >> 3, h = bh & 7;
  const int t = threadIdx.x;
  const int mf = flags[2];
  __shared__ float ekb[16 * 65];
  __shared__ float vvb[16 * 65];
  const int tok  = t >> 4, d0 = (t & 15) * 4;
  const int down = t >> 2, e0 = (t & 3) * 16;
  float acc[16];
  #pragma unroll
  for (int i = 0; i < 16; ++i) acc[i] = 0.f;
  float dsum = 0.f;

  for (int g = 0; g < 16; ++g) {
    int row = b * N_ + chunk * 256 + g * 16 + tok;
    bool mk = mask_at(mask, mf, row);
    __syncthreads();   // prev accumulate's LDS reads done
    const ST* kp = qkv + (size_t)row * E3_ + DIM_     + h * DH_ + d0;
    const ST* vp = qkv + (size_t)row * E3_ + 2 * DIM_ + h * DH_ + d0;
    #pragma unroll
    for (int j = 0; j < 4; ++j) {
      ekb[tok * 65 + d0 + j] = mk ? __expf(ldst(kp + j)) : 0.f;
      vvb[tok * 65 + d0 + j] = mk ? ldst(vp + j) : 0.f;
    }
    __syncthreads();
    #pragma unroll 4
    for (int nn = 0; nn < 16; ++nn) {
      float ekd = ekb[nn * 65 + down];
      if (e0 == 0) dsum += ekd;
      #pragma unroll
      for (int i = 0; i < 16; ++i) acc[i] += ekd * vvb[nn * 65 + e0 + i];
    }
  }
  float* kvp = kvbuf + (size_t)bh * 4096 + down * 64 + e0;
  #pragma unroll
  for (int i = 0; i < 16; ++i) atomicAdd(&kvp[i], acc[i]);
  if (e0 == 0) atomicAdd(&denom[bh * 64 + down], dsum);
}

// ---------------- output from materialized q ----------------
template<typename ST>
__global__ __launch_bounds__(256)
void out_pass(const ST* __restrict__ qkv,
              const float* __restrict__ kvbuf, const float* __restrict__ denom,
              float* __restrict__ out)
{
  const int chunk = blockIdx.x;   // 0..15
  const int bh    = blockIdx.y;   // 0..31
  const int b = bh >> 3, h = bh & 7;
  const int t = threadIdx.x;
  __shared__ float kvn[64][68];
  __shared__ float qsm[16 * 65];
  for (int i = t; i < 4096; i += 256) {
    int d = i >> 6, e = i & 63;
    kvn[d][e] = kvbuf[(size_t)bh * 4096 + i] / denom[bh * 64 + d];
  }
  const int tok = t >> 4, p = t & 15, d0 = p * 4;

  for (int g = 0; g < 16; ++g) {
    int row = b * N_ + chunk * 256 + g * 16 + tok;
    __syncthreads();   // kvn ready (g=0) / prev matvec's qsm reads done
    float qreg[4];
    const ST* qp = qkv + (size_t)row * E3_ + h * DH_ + d0;
    #pragma unroll
    for (int j = 0; j < 4; ++j) qreg[j] = ldst(qp + j);
    // softmax over 64 dims = 16 lanes x 4 regs (bias already added in GEMM)
    float mx = fmaxf(fmaxf(qreg[0], qreg[1]), fmaxf(qreg[2], qreg[3]));
    #pragma unroll
    for (int o = 1; o < 16; o <<= 1) mx = fmaxf(mx, __shfl_xor(mx, o, 16));
    float s = 0.f;
    #pragma unroll
    for (int j = 0; j < 4; ++j) { qreg[j] = __expf(qreg[j] - mx); s += qreg[j]; }
    #pragma unroll
    for (int o = 1; o < 16; o <<= 1) s += __shfl_xor(s, o, 16);
    float inv = 1.f / s;
    #pragma unroll
    for (int j = 0; j < 4; ++j) qsm[tok * 65 + d0 + j] = qreg[j] * inv;
    __syncthreads();
    {
      int e0 = p * 4;
      float ov[4] = {0.f,0.f,0.f,0.f};
      #pragma unroll 4
      for (int d = 0; d < 64; ++d) {
        float qd = qsm[tok * 65 + d];
        #pragma unroll
        for (int j = 0; j < 4; ++j) ov[j] += qd * kvn[d][e0 + j];
      }
      size_t ob = (size_t)row * DIM_ + h * DH_ + e0;
      #pragma unroll
      for (int j = 0; j < 4; ++j) out[ob + j] = ov[j];
    }
  }
}

// ================= round-5 fused fallback (validated, used only if ws too small) =================
__device__ inline void stage_x_f(float (*xa)[516], const void* x, int xf, int brow0, int t)
{
  if (xf) {
    const float* xp = (const float*)x;
    #pragma unroll
    for (int s = 0; s < 8; ++s) {
      int row = (t >> 7) + 2 * s, col = (t & 127) * 4;
      *(float4*)&xa[row][col] = *(const float4*)(xp + ((size_t)(brow0 + row)) * DIM_ + col);
    }
  } else {
    const unsigned short* xp = (const unsigned short*)x;
    #pragma unroll
    for (int s = 0; s < 8; ++s) {
      int row = (t >> 7) + 2 * s, col = (t & 127) * 4;
      const unsigned short* pp = xp + ((size_t)(brow0 + row)) * DIM_ + col;
      #pragma unroll
      for (int j = 0; j < 4; ++j) xa[row][col + j] = bf2f(pp[j]);
    }
  }
}

__global__ __launch_bounds__(256)
void kv_pass_fused(const void* __restrict__ x, const void* __restrict__ w,
                   const void* __restrict__ bias, const void* __restrict__ mask,
                   const int* __restrict__ flags,
                   float* __restrict__ kvbuf, float* __restrict__ denom)
{
  const int chunk = blockIdx.x, bh = blockIdx.y;
  const int b = bh >> 3, h = bh & 7;
  const int t = threadIdx.x;
  const int xf = flags[0], wf = flags[1], mf = flags[2];
  __shared__ float xa[16][516];
  __shared__ float Wb[64][130];
  float* ekb = &Wb[0][0];
  float* vvb = &Wb[0][0] + 16 * 65;
  const int tok = t >> 4, d0 = (t & 15) * 4;
  const int down = t >> 2, e0 = (t & 3) * 16;
  float acc[16];
  #pragma unroll
  for (int i = 0; i < 16; ++i) acc[i] = 0.f;
  float dsum = 0.f;
  for (int g = 0; g < 16; ++g) {
    const int n0 = chunk * 256 + g * 16;
    __syncthreads();
    stage_x_f(xa, x, xf, b * N_ + n0, t);
    float kreg[4] = {0,0,0,0}, vreg[4] = {0,0,0,0};
    for (int cc = 0; cc < 8; ++cc) {
      __syncthreads();
      {
        int c0 = (t >> 7) * 32, col = t & 127;
        int wc = (col < 64) ? (512 + h * DH_ + col) : (1024 + h * DH_ + (col - 64));
        #pragma unroll 8
        for (int j = 0; j < 32; ++j)
          Wb[c0 + j][col] = gread(w, wf, (size_t)(cc * 64 + c0 + j) * E3_ + wc);
      }
      __syncthreads();
      #pragma unroll 4
      for (int c = 0; c < 64; ++c) {
        float xv = xa[tok][cc * 64 + c];
        #pragma unroll
        for (int j = 0; j < 4; ++j) {
          kreg[j] += xv * Wb[c][d0 + j];
          vreg[j] += xv * Wb[c][64 + d0 + j];
        }
      }
    }
    bool mk = mask_at(mask, mf, b * N_ + n0 + tok);
    __syncthreads();
    #pragma unroll
    for (int j = 0; j < 4; ++j) {
      float kvl = kreg[j] + gread(bias, wf, 512  + h * DH_ + d0 + j);
      float vvl = vreg[j] + gread(bias, wf, 1024 + h * DH_ + d0 + j);
      ekb[tok * 65 + d0 + j] = mk ? __expf(kvl) : 0.f;
      vvb[tok * 65 + d0 + j] = mk ? vvl : 0.f;
    }
    __syncthreads();
    #pragma unroll 4
    for (int nn = 0; nn < 16; ++nn) {
      float ekd = ekb[nn * 65 + down];
      if (e0 == 0) dsum += ekd;
      #pragma unroll
      for (int i = 0; i < 16; ++i) acc[i] += ekd * vvb[nn * 65 + e0 + i];
    }
  }
  float* kvp = kvbuf + (size_t)bh * 4096 + down * 64 + e0;
  #pragma unroll
  for (int i = 0; i < 16; ++i) atomicAdd(&kvp[i], acc[i]);
  if (e0 == 0) atomicAdd(&denom[bh * 64 + down], dsum);
}

__global__ __launch_bounds__(256)
void out_pass_fused(const void* __restrict__ x, const void* __restrict__ w,
                    const void* __restrict__ bias, const int* __restrict__ flags,
                    const float* __restrict__ kvbuf, const float* __restrict__ denom,
                    float* __restrict__ out)
{
  const int chunk = blockIdx.x, bh = blockIdx.y;
  const int b = bh >> 3, h = bh & 7;
  const int t = threadIdx.x;
  const int xf = flags[0], wf = flags[1];
  __shared__ float xa[16][516];
  __shared__ float Wq[64][66];
  __shared__ float kvn[64][68];
  float* qsm = &Wq[0][0];
  for (int i = t; i < 4096; i += 256) {
    int d = i >> 6, e = i & 63;
    kvn[d][e] = kvbuf[(size_t)bh * 4096 + i] / denom[bh * 64 + d];
  }
  const int tok = t >> 4, p = t & 15, d0 = p * 4;
  for (int g = 0; g < 16; ++g) {
    const int n0 = chunk * 256 + g * 16;
    __syncthreads();
    stage_x_f(xa, x, xf, b * N_ + n0, t);
    float qreg[4] = {0,0,0,0};
    for (int cc = 0; cc < 8; ++cc) {
      __syncthreads();
      {
        int col = t & 63, c0 = (t >> 6) * 16;
        #pragma unroll 8
        for (int j = 0; j < 16; ++j)
          Wq[c0 + j][col] = gread(w, wf, (size_t)(cc * 64 + c0 + j) * E3_ + h * DH_ + col);
      }
      __syncthreads();
      #pragma unroll 4
      for (int c = 0; c < 64; ++c) {
        float xv = xa[tok][cc * 64 + c];
        #pragma unroll
        for (int j = 0; j < 4; ++j) qreg[j] += xv * Wq[c][d0 + j];
      }
    }
    #pragma unroll
    for (int j = 0; j < 4; ++j) qreg[j] += gread(bias, wf, h * DH_ + d0 + j);
    float mx = fmaxf(fmaxf(qreg[0], qreg[1]), fmaxf(qreg[2], qreg[3]));
    #pragma unroll
    for (int o = 1; o < 16; o <<= 1) mx = fmaxf(mx, __shfl_xor(mx, o, 16));
    float s = 0.f;
    #pragma unroll
    for (int j = 0; j < 4; ++j) { qreg[j] = __expf(qreg[j] - mx); s += qreg[j]; }
    #pragma unroll
    for (int o = 1; o < 16; o <<= 1) s += __shfl_xor(s, o, 16);
    float inv = 1.f / s;
    __syncthreads();
    #pragma unroll
    for (int j = 0; j < 4; ++j) qsm[tok * 65 + d0 + j] = qreg[j] * inv;
    __syncthreads();
    {
      int e0 = p * 4;
      float ov[4] = {0,0,0,0};
      #pragma unroll 4
      for (int d = 0; d < 64; ++d) {
        float qd = qsm[tok * 65 + d];
        #pragma unroll
        for (int j = 0; j < 4; ++j) ov[j] += qd * kvn[d][e0 + j];
      }
      size_t ob = ((size_t)(b * N_ + n0 + tok)) * DIM_ + h * DH_ + e0;
      #pragma unroll
      for (int j = 0; j < 4; ++j) out[ob + j] = ov[j];
    }
  }
}

extern "C" void kernel_launch(void* const* d_in, const int* in_sizes, int n_in,
                              void* d_out, int out_size, void* d_ws, size_t ws_size,
                              hipStream_t stream)
{
  const void* x    = d_in[0];
  const void* mask = d_in[1];
  const void* w    = d_in[2];
  const void* bias = d_in[3];
  float* out = (float*)d_out;

  char* ws = (char*)d_ws;
  const size_t offFlg = 0;                                  // 256 B
  const size_t offKv  = 256;
  const size_t offDen = offKv + 32 * 4096 * 4;
  const size_t offXb  = offDen + 32 * 64 * 4;               // + pad lands 256-aligned
  const size_t offWT  = offXb + (size_t)M_ * DIM_ * 2;
  const size_t offQkv = offWT + (size_t)E3_ * DIM_ * 2;
  const size_t qkvN   = (size_t)M_ * E3_;
  const size_t need32 = offQkv + qkvN * 4;                  // ~119.5 MB
  const size_t need16 = offQkv + qkvN * 2;                  // ~69.2 MB

  int*   flags = (int*)(ws + offFlg);
  float* kvbuf = (float*)(ws + offKv);
  float* denom = (float*)(ws + offDen);

  hipMemsetAsync(kvbuf, 0, 32 * 4096 * 4 + 32 * 64 * 4, stream);
  detect_fmt<<<1, 256, 0, stream>>>((const unsigned int*)x, (const unsigned int*)w,
                                    (const unsigned int*)mask, flags);

  dim3 ga(16, 32);   // attention kernels: (token-chunk, bh)
  if (ws_size >= need16) {
    unsigned short* xb  = (unsigned short*)(ws + offXb);
    unsigned short* wbT = (unsigned short*)(ws + offWT);
    conv_x<<<(int)((size_t)M_ * DIM_ / 4 / 256), 256, 0, stream>>>(x, xb, flags);
    dim3 gt(E3_ / 64, DIM_ / 64);
    conv_wT<<<gt, 256, 0, stream>>>(w, wbT, flags);
    dim3 gg(E3_ / 128, M_ / 128);   // 12 x 128
    if (ws_size >= need32) {
      float* qkv = (float*)(ws + offQkv);
      qkv_gemm<float><<<gg, 256, 0, stream>>>(xb, wbT, bias, flags, qkv);
      kv_accum<float><<<ga, 256, 0, stream>>>(qkv, mask, flags, kvbuf, denom);
      out_pass<float><<<ga, 256, 0, stream>>>(qkv, kvbuf, denom, out);
    } else {
      unsigned short* qkv = (unsigned short*)(ws + offQkv);
      qkv_gemm<unsigned short><<<gg, 256, 0, stream>>>(xb, wbT, bias, flags, qkv);
      kv_accum<unsigned short><<<ga, 256, 0, stream>>>(qkv, mask, flags, kvbuf, denom);
      out_pass<unsigned short><<<ga, 256, 0, stream>>>(qkv, kvbuf, denom, out);
    }
  } else {
    kv_pass_fused <<<ga, 256, 0, stream>>>(x, w, bias, mask, flags, kvbuf, denom);
    out_pass_fused<<<ga, 256, 0, stream>>>(x, w, bias, flags, kvbuf, denom, out);
  }
}

// Round 7
// 235.434 us; speedup vs baseline: 13.1170x; 1.6439x over previous
//
#include <hip/hip_runtime.h>
#include <stdint.h>

#define B_   4
#define N_   4096
#define DIM_ 512
#define H_   8
#define DH_  64
#define E3_  1536
#define M_   (B_*N_)   // 16384

typedef __attribute__((ext_vector_type(8))) __bf16 bf16x8;
typedef __attribute__((ext_vector_type(8))) unsigned short ushort8;
typedef __attribute__((ext_vector_type(4))) float f32x4;

__device__ inline float bf2f(unsigned short u){ return __uint_as_float(((unsigned)u)<<16); }
__device__ inline unsigned short f2bf(float f){
  unsigned u = __float_as_uint(f);
  u += 0x7FFFu + ((u>>16)&1u);   // RNE
  return (unsigned short)(u>>16);
}

// ---------------- format detection ----------------
// flags[0]: x fp32?  flags[1]: W/bias fp32?  flags[2]: mask 0=i32,1=f32,2=bf16,3=u8
__global__ void detect_fmt(const unsigned int* __restrict__ xw,
                           const unsigned int* __restrict__ ww,
                           const unsigned int* __restrict__ mw,
                           int* __restrict__ flags)
{
  __shared__ int cnt[2];
  __shared__ int ok[3];
  if (threadIdx.x < 2) cnt[threadIdx.x] = 0;
  if (threadIdx.x < 3) ok[threadIdx.x] = 1;
  __syncthreads();
  int hx = 0, hw = 0;
  for (int i = threadIdx.x; i < 1024; i += 256) {
    if (((xw[i] >> 7) & 0xFFu) > 140u) hx++;
    if (((ww[i] >> 7) & 0xFFu) > 140u) hw++;
  }
  int okInt = 1, okF32 = 1, okBf = 1;
  for (int i = threadIdx.x; i < 4096; i += 256) {
    unsigned w = mw[i];
    if (w > 1u) okInt = 0;
    if (w != 0u && w != 0x3F800000u) okF32 = 0;
    unsigned short a = (unsigned short)(w & 0xFFFFu), b = (unsigned short)(w >> 16);
    if (!((a == 0 || a == 0x3F80u) && (b == 0 || b == 0x3F80u))) okBf = 0;
  }
  atomicAdd(&cnt[0], hx);
  atomicAdd(&cnt[1], hw);
  if (!okInt) atomicAnd(&ok[0], 0);
  if (!okF32) atomicAnd(&ok[1], 0);
  if (!okBf)  atomicAnd(&ok[2], 0);
  __syncthreads();
  if (threadIdx.x == 0) {
    flags[0] = cnt[0] > 64 ? 1 : 0;
    flags[1] = cnt[1] > 64 ? 1 : 0;
    flags[2] = ok[0] ? 0 : (ok[1] ? 1 : (ok[2] ? 2 : 3));
  }
}

__device__ inline bool mask_at(const void* m, int flag, int idx){
  if (flag == 0) return ((const int*)m)[idx] != 0;
  if (flag == 1) return ((const float*)m)[idx] != 0.f;
  if (flag == 2) return ((const unsigned short*)m)[idx] != 0;
  return ((const unsigned char*)m)[idx] != 0;
}
__device__ inline float gread(const void* p, int f32, size_t i){
  return f32 ? ((const float*)p)[i] : bf2f(((const unsigned short*)p)[i]);
}

// ---------------- convert x -> bf16 ----------------
__global__ __launch_bounds__(256)
void conv_x(const void* __restrict__ src, unsigned short* __restrict__ dst,
            const int* __restrict__ flags)
{
  const int f = flags[0];
  size_t i = ((size_t)blockIdx.x * 256 + threadIdx.x) * 4;
  #pragma unroll
  for (int j = 0; j < 4; ++j) dst[i + j] = f2bf(gread(src, f, i + j));
}

// ---------------- convert + transpose W: wbT[n][k] = W[k][n] ----------------
__global__ __launch_bounds__(256)
void conv_wT(const void* __restrict__ w, unsigned short* __restrict__ wbT,
             const int* __restrict__ flags)
{
  const int f = flags[1];
  __shared__ unsigned short ts[64][66];
  const int n0 = blockIdx.x * 64;
  const int k0 = blockIdx.y * 64;
  const int t = threadIdx.x;
  const int c = t & 63;
  #pragma unroll
  for (int p = 0; p < 16; ++p) {
    int r = (t >> 6) * 16 + p;
    ts[r][c] = f2bf(gread(w, f, (size_t)(k0 + r) * E3_ + n0 + c));
  }
  __syncthreads();
  #pragma unroll
  for (int p = 0; p < 16; ++p) {
    int nrow = (t >> 6) * 16 + p;
    wbT[(size_t)(n0 + nrow) * DIM_ + k0 + c] = ts[c][nrow];
  }
}

// ---------------- QKV GEMM (MFMA) + fused mask/exp epilogue ----------------
// 128x128 tile, BK=32, 4 waves x (4x4) 16x16x32 fragments.
// Col-blocks 0..3 = q -> qb[row][512] bf16; 4..7 = k -> ekg; 8..11 = v -> vmg.
// ekg/vmg layout (MFMA-frag-friendly): [bh][nn>>3][d][nn&7] bf16.
__global__ __launch_bounds__(256)
void qkv_gemm_fused(const unsigned short* __restrict__ xb,   // M x 512 bf16
                    const unsigned short* __restrict__ wbT,  // 1536 x 512 bf16 (W^T)
                    const void* __restrict__ bias, const void* __restrict__ mask,
                    const int* __restrict__ flags,
                    unsigned short* __restrict__ qb,
                    unsigned short* __restrict__ ekg,
                    unsigned short* __restrict__ vmg)
{
  const int wf = flags[1], mf = flags[2];
  __shared__ alignas(16) unsigned short As[4][128][8];  // [k>>3][m][k&7]
  __shared__ alignas(16) unsigned short Bs[4][128][8];
  const int t = threadIdx.x;
  const int lane = t & 63, wv = t >> 6;
  const int quad = lane >> 4, l15 = lane & 15;
  const int m0 = blockIdx.y * 128, n0 = blockIdx.x * 128;
  const int mw = (wv & 1) * 64, nw = (wv >> 1) * 64;

  f32x4 acc[4][4];
  #pragma unroll
  for (int i = 0; i < 4; ++i)
    #pragma unroll
    for (int j = 0; j < 4; ++j) acc[i][j] = (f32x4){0.f,0.f,0.f,0.f};

  const int srow = t >> 1, sks = (t & 1) * 16;
  for (int kk = 0; kk < DIM_; kk += 32) {
    __syncthreads();
    {
      const ushort8* srcA = (const ushort8*)(xb + (size_t)(m0 + srow) * DIM_ + kk + sks);
      *(ushort8*)&As[(sks >> 3) + 0][srow][0] = srcA[0];
      *(ushort8*)&As[(sks >> 3) + 1][srow][0] = srcA[1];
      const ushort8* srcB = (const ushort8*)(wbT + (size_t)(n0 + srow) * DIM_ + kk + sks);
      *(ushort8*)&Bs[(sks >> 3) + 0][srow][0] = srcB[0];
      *(ushort8*)&Bs[(sks >> 3) + 1][srow][0] = srcB[1];
    }
    __syncthreads();
    ushort8 af[4], bfr[4];
    #pragma unroll
    for (int i = 0; i < 4; ++i) {
      af[i]  = *(const ushort8*)&As[quad][mw + i * 16 + l15][0];
      bfr[i] = *(const ushort8*)&Bs[quad][nw + i * 16 + l15][0];
    }
    #pragma unroll
    for (int i = 0; i < 4; ++i)
      #pragma unroll
      for (int j = 0; j < 4; ++j)
        acc[i][j] = __builtin_amdgcn_mfma_f32_16x16x32_bf16(
            __builtin_bit_cast(bf16x8, af[i]), __builtin_bit_cast(bf16x8, bfr[j]),
            acc[i][j], 0, 0, 0);
  }

  const int mode = blockIdx.x >> 2;   // 0=q, 1=k, 2=v (block-uniform)
  if (mode == 0) {
    #pragma unroll
    for (int j = 0; j < 4; ++j) {
      int col = n0 + nw + j * 16 + l15;   // 0..511
      float bv = gread(bias, wf, col);
      #pragma unroll
      for (int i = 0; i < 4; ++i)
        #pragma unroll
        for (int r = 0; r < 4; ++r) {
          int row = m0 + mw + i * 16 + quad * 4 + r;
          qb[(size_t)row * 512 + col] = f2bf(acc[i][j][r] + bv);
        }
    }
  } else {
    unsigned short* dstbuf = (mode == 1) ? ekg : vmg;
    float bj[4]; int hj[4], dj[4];
    #pragma unroll
    for (int j = 0; j < 4; ++j) {
      int col = n0 + nw + j * 16 + l15;
      bj[j] = gread(bias, wf, col);
      int rel = col - mode * 512;
      hj[j] = rel >> 6; dj[j] = rel & 63;
    }
    #pragma unroll
    for (int i = 0; i < 4; ++i)
      #pragma unroll
      for (int r = 0; r < 4; ++r) {
        int row = m0 + mw + i * 16 + quad * 4 + r;
        bool mk = mask_at(mask, mf, row);
        int b = row >> 12, nn = row & 4095;
        size_t base = (size_t)(nn >> 3) * 512 + (nn & 7);
        #pragma unroll
        for (int j = 0; j < 4; ++j) {
          float val = acc[i][j][r] + bj[j];
          val = (mode == 1) ? (mk ? __expf(val) : 0.f) : (mk ? val : 0.f);
          dstbuf[(size_t)(b * 8 + hj[j]) * 262144 + base + (size_t)dj[j] * 8] = f2bf(val);
        }
      }
  }
}

// ---------------- kv GEMM: kv[bh][d][e] = sum_n ek[n,d]*vm[n,e] (MFMA) + denom ----------------
__global__ __launch_bounds__(256)
void kv_gemm(const unsigned short* __restrict__ ekg,
             const unsigned short* __restrict__ vmg,
             float* __restrict__ kvbuf, float* __restrict__ denom)
{
  const int kc = blockIdx.x;  // 0..15 (256-token chunk)
  const int bh = blockIdx.y;  // 0..31
  const int t  = threadIdx.x;
  const int lane = t & 63, wv = t >> 6;
  const int quad = lane >> 4, l15 = lane & 15;
  __shared__ alignas(16) unsigned short ekS[16384];  // [ktl 0..31][d 0..63][8]
  __shared__ alignas(16) unsigned short vmS[16384];
  const size_t gbase = (size_t)bh * 262144 + (size_t)kc * 16384;
  #pragma unroll
  for (int i = 0; i < 8; ++i) {
    int idx = (t + i * 256) * 8;
    *(ushort8*)&ekS[idx] = *(const ushort8*)&ekg[gbase + idx];
    *(ushort8*)&vmS[idx] = *(const ushort8*)&vmg[gbase + idx];
  }
  __syncthreads();
  {  // denom partial: sum ek over this chunk's tokens, per d
    int d = t & 63, g0 = (t >> 6) * 8;
    float s = 0.f;
    #pragma unroll
    for (int kt = 0; kt < 8; ++kt) {
      ushort8 v = *(const ushort8*)&ekS[((g0 + kt) * 64 + d) * 8];
      #pragma unroll
      for (int j = 0; j < 8; ++j) s += bf2f(v[j]);
    }
    atomicAdd(&denom[bh * 64 + d], s);
  }
  f32x4 acc[4];
  #pragma unroll
  for (int j = 0; j < 4; ++j) acc[j] = (f32x4){0.f,0.f,0.f,0.f};
  #pragma unroll 2
  for (int ks = 0; ks < 8; ++ks) {
    ushort8 af = *(const ushort8*)&ekS[((ks * 4 + quad) * 64 + wv * 16 + l15) * 8];
    #pragma unroll
    for (int jt = 0; jt < 4; ++jt) {
      ushort8 bf8 = *(const ushort8*)&vmS[((ks * 4 + quad) * 64 + jt * 16 + l15) * 8];
      acc[jt] = __builtin_amdgcn_mfma_f32_16x16x32_bf16(
          __builtin_bit_cast(bf16x8, af), __builtin_bit_cast(bf16x8, bf8),
          acc[jt], 0, 0, 0);
    }
  }
  #pragma unroll
  for (int jt = 0; jt < 4; ++jt)
    #pragma unroll
    for (int r = 0; r < 4; ++r)
      atomicAdd(&kvbuf[bh * 4096 + (wv * 16 + quad * 4 + r) * 64 + jt * 16 + l15],
                acc[jt][r]);
}

// ---------------- output: q-softmax + kv_norm^T q (q prefetched) ----------------
__global__ __launch_bounds__(256)
void out_pass(const unsigned short* __restrict__ qb,
              const float* __restrict__ kvbuf, const float* __restrict__ denom,
              float* __restrict__ out)
{
  const int chunk = blockIdx.x, bh = blockIdx.y;
  const int b = bh >> 3, h = bh & 7;
  const int t = threadIdx.x;
  __shared__ float kvn[64][68];
  __shared__ float qsm[16 * 65];
  for (int i = t; i < 4096; i += 256) {
    int d = i >> 6, e = i & 63;
    kvn[d][e] = kvbuf[(size_t)bh * 4096 + i] / denom[bh * 64 + d];
  }
  const int tok = t >> 4, p = t & 15, d0 = p * 4;

  float qreg[4];
  {
    int row = b * N_ + chunk * 256 + tok;
    uint2 qw = *(const uint2*)(qb + (size_t)row * 512 + h * DH_ + d0);
    qreg[0] = bf2f((unsigned short)(qw.x & 0xffff));
    qreg[1] = bf2f((unsigned short)(qw.x >> 16));
    qreg[2] = bf2f((unsigned short)(qw.y & 0xffff));
    qreg[3] = bf2f((unsigned short)(qw.y >> 16));
  }
  for (int g = 0; g < 16; ++g) {
    int row = b * N_ + chunk * 256 + g * 16 + tok;
    float mx = fmaxf(fmaxf(qreg[0], qreg[1]), fmaxf(qreg[2], qreg[3]));
    #pragma unroll
    for (int o = 1; o < 16; o <<= 1) mx = fmaxf(mx, __shfl_xor(mx, o, 16));
    float ex[4]; float s = 0.f;
    #pragma unroll
    for (int j = 0; j < 4; ++j) { ex[j] = __expf(qreg[j] - mx); s += ex[j]; }
    #pragma unroll
    for (int o = 1; o < 16; o <<= 1) s += __shfl_xor(s, o, 16);
    float inv = 1.f / s;
    __syncthreads();   // kvn ready (g=0) / prev matvec's qsm reads done
    #pragma unroll
    for (int j = 0; j < 4; ++j) qsm[tok * 65 + d0 + j] = ex[j] * inv;
    if (g < 15) {      // prefetch next group's q (overlaps barrier + matvec)
      uint2 qw = *(const uint2*)(qb + (size_t)(row + 16) * 512 + h * DH_ + d0);
      qreg[0] = bf2f((unsigned short)(qw.x & 0xffff));
      qreg[1] = bf2f((unsigned short)(qw.x >> 16));
      qreg[2] = bf2f((unsigned short)(qw.y & 0xffff));
      qreg[3] = bf2f((unsigned short)(qw.y >> 16));
    }
    __syncthreads();
    int e0 = p * 4;
    float ov[4] = {0.f,0.f,0.f,0.f};
    #pragma unroll 4
    for (int d = 0; d < 64; ++d) {
      float qd = qsm[tok * 65 + d];
      #pragma unroll
      for (int j = 0; j < 4; ++j) ov[j] += qd * kvn[d][e0 + j];
    }
    size_t ob = (size_t)row * DIM_ + h * DH_ + e0;
    #pragma unroll
    for (int j = 0; j < 4; ++j) out[ob + j] = ov[j];
  }
}

// ================= round-5 fused fallback (only if ws too small) =================
__device__ inline void stage_x_f(float (*xa)[516], const void* x, int xf, int brow0, int t)
{
  if (xf) {
    const float* xp = (const float*)x;
    #pragma unroll
    for (int s = 0; s < 8; ++s) {
      int row = (t >> 7) + 2 * s, col = (t & 127) * 4;
      *(float4*)&xa[row][col] = *(const float4*)(xp + ((size_t)(brow0 + row)) * DIM_ + col);
    }
  } else {
    const unsigned short* xp = (const unsigned short*)x;
    #pragma unroll
    for (int s = 0; s < 8; ++s) {
      int row = (t >> 7) + 2 * s, col = (t & 127) * 4;
      const unsigned short* pp = xp + ((size_t)(brow0 + row)) * DIM_ + col;
      #pragma unroll
      for (int j = 0; j < 4; ++j) xa[row][col + j] = bf2f(pp[j]);
    }
  }
}

__global__ __launch_bounds__(256)
void kv_pass_fused(const void* __restrict__ x, const void* __restrict__ w,
                   const void* __restrict__ bias, const void* __restrict__ mask,
                   const int* __restrict__ flags,
                   float* __restrict__ kvbuf, float* __restrict__ denom)
{
  const int chunk = blockIdx.x, bh = blockIdx.y;
  const int b = bh >> 3, h = bh & 7;
  const int t = threadIdx.x;
  const int xf = flags[0], wf = flags[1], mf = flags[2];
  __shared__ float xa[16][516];
  __shared__ float Wb[64][130];
  float* ekb = &Wb[0][0];
  float* vvb = &Wb[0][0] + 16 * 65;
  const int tok = t >> 4, d0 = (t & 15) * 4;
  const int down = t >> 2, e0 = (t & 3) * 16;
  float acc[16];
  #pragma unroll
  for (int i = 0; i < 16; ++i) acc[i] = 0.f;
  float dsum = 0.f;
  for (int g = 0; g < 16; ++g) {
    const int n0 = chunk * 256 + g * 16;
    __syncthreads();
    stage_x_f(xa, x, xf, b * N_ + n0, t);
    float kreg[4] = {0,0,0,0}, vreg[4] = {0,0,0,0};
    for (int cc = 0; cc < 8; ++cc) {
      __syncthreads();
      {
        int c0 = (t >> 7) * 32, col = t & 127;
        int wc = (col < 64) ? (512 + h * DH_ + col) : (1024 + h * DH_ + (col - 64));
        #pragma unroll 8
        for (int j = 0; j < 32; ++j)
          Wb[c0 + j][col] = gread(w, wf, (size_t)(cc * 64 + c0 + j) * E3_ + wc);
      }
      __syncthreads();
      #pragma unroll 4
      for (int c = 0; c < 64; ++c) {
        float xv = xa[tok][cc * 64 + c];
        #pragma unroll
        for (int j = 0; j < 4; ++j) {
          kreg[j] += xv * Wb[c][d0 + j];
          vreg[j] += xv * Wb[c][64 + d0 + j];
        }
      }
    }
    bool mk = mask_at(mask, mf, b * N_ + n0 + tok);
    __syncthreads();
    #pragma unroll
    for (int j = 0; j < 4; ++j) {
      float kvl = kreg[j] + gread(bias, wf, 512  + h * DH_ + d0 + j);
      float vvl = vreg[j] + gread(bias, wf, 1024 + h * DH_ + d0 + j);
      ekb[tok * 65 + d0 + j] = mk ? __expf(kvl) : 0.f;
      vvb[tok * 65 + d0 + j] = mk ? vvl : 0.f;
    }
    __syncthreads();
    #pragma unroll 4
    for (int nn = 0; nn < 16; ++nn) {
      float ekd = ekb[nn * 65 + down];
      if (e0 == 0) dsum += ekd;
      #pragma unroll
      for (int i = 0; i < 16; ++i) acc[i] += ekd * vvb[nn * 65 + e0 + i];
    }
  }
  float* kvp = kvbuf + (size_t)bh * 4096 + down * 64 + e0;
  #pragma unroll
  for (int i = 0; i < 16; ++i) atomicAdd(&kvp[i], acc[i]);
  if (e0 == 0) atomicAdd(&denom[bh * 64 + down], dsum);
}

__global__ __launch_bounds__(256)
void out_pass_fused(const void* __restrict__ x, const void* __restrict__ w,
                    const void* __restrict__ bias, const int* __restrict__ flags,
                    const float* __restrict__ kvbuf, const float* __restrict__ denom,
                    float* __restrict__ out)
{
  const int chunk = blockIdx.x, bh = blockIdx.y;
  const int b = bh >> 3, h = bh & 7;
  const int t = threadIdx.x;
  const int xf = flags[0], wf = flags[1];
  __shared__ float xa[16][516];
  __shared__ float Wq[64][66];
  __shared__ float kvn[64][68];
  float* qsm = &Wq[0][0];
  for (int i = t; i < 4096; i += 256) {
    int d = i >> 6, e = i & 63;
    kvn[d][e] = kvbuf[(size_t)bh * 4096 + i] / denom[bh * 64 + d];
  }
  const int tok = t >> 4, p = t & 15, d0 = p * 4;
  for (int g = 0; g < 16; ++g) {
    const int n0 = chunk * 256 + g * 16;
    __syncthreads();
    stage_x_f(xa, x, xf, b * N_ + n0, t);
    float qreg[4] = {0,0,0,0};
    for (int cc = 0; cc < 8; ++cc) {
      __syncthreads();
      {
        int col = t & 63, c0 = (t >> 6) * 16;
        #pragma unroll 8
        for (int j = 0; j < 16; ++j)
          Wq[c0 + j][col] = gread(w, wf, (size_t)(cc * 64 + c0 + j) * E3_ + h * DH_ + col);
      }
      __syncthreads();
      #pragma unroll 4
      for (int c = 0; c < 64; ++c) {
        float xv = xa[tok][cc * 64 + c];
        #pragma unroll
        for (int j = 0; j < 4; ++j) qreg[j] += xv * Wq[c][d0 + j];
      }
    }
    #pragma unroll
    for (int j = 0; j < 4; ++j) qreg[j] += gread(bias, wf, h * DH_ + d0 + j);
    float mx = fmaxf(fmaxf(qreg[0], qreg[1]), fmaxf(qreg[2], qreg[3]));
    #pragma unroll
    for (int o = 1; o < 16; o <<= 1) mx = fmaxf(mx, __shfl_xor(mx, o, 16));
    float s = 0.f;
    #pragma unroll
    for (int j = 0; j < 4; ++j) { qreg[j] = __expf(qreg[j] - mx); s += qreg[j]; }
    #pragma unroll
    for (int o = 1; o < 16; o <<= 1) s += __shfl_xor(s, o, 16);
    float inv = 1.f / s;
    __syncthreads();
    #pragma unroll
    for (int j = 0; j < 4; ++j) qsm[tok * 65 + d0 + j] = qreg[j] * inv;
    __syncthreads();
    {
      int e0 = p * 4;
      float ov[4] = {0,0,0,0};
      #pragma unroll 4
      for (int d = 0; d < 64; ++d) {
        float qd = qsm[tok * 65 + d];
        #pragma unroll
        for (int j = 0; j < 4; ++j) ov[j] += qd * kvn[d][e0 + j];
      }
      size_t ob = ((size_t)(b * N_ + n0 + tok)) * DIM_ + h * DH_ + e0;
      #pragma unroll
      for (int j = 0; j < 4; ++j) out[ob + j] = ov[j];
    }
  }
}

extern "C" void kernel_launch(void* const* d_in, const int* in_sizes, int n_in,
                              void* d_out, int out_size, void* d_ws, size_t ws_size,
                              hipStream_t stream)
{
  const void* x    = d_in[0];
  const void* mask = d_in[1];
  const void* w    = d_in[2];
  const void* bias = d_in[3];
  float* out = (float*)d_out;

  char* ws = (char*)d_ws;
  const size_t offFlg = 0;
  const size_t offKv  = 256;
  const size_t offDen = offKv + 32 * 4096 * 4;
  const size_t offXb  = offDen + 32 * 64 * 4;
  const size_t offWT  = offXb + (size_t)M_ * DIM_ * 2;
  const size_t offQ   = offWT + (size_t)E3_ * DIM_ * 2;
  const size_t offEk  = offQ  + (size_t)M_ * DIM_ * 2;
  const size_t offVm  = offEk + (size_t)M_ * DH_ * H_ * 2;   // 32*4096*64 bf16
  const size_t need   = offVm + (size_t)M_ * DH_ * H_ * 2;   // == round-6 proven bound

  int*   flags = (int*)(ws + offFlg);
  float* kvbuf = (float*)(ws + offKv);
  float* denom = (float*)(ws + offDen);

  hipMemsetAsync(kvbuf, 0, 32 * 4096 * 4 + 32 * 64 * 4, stream);
  detect_fmt<<<1, 256, 0, stream>>>((const unsigned int*)x, (const unsigned int*)w,
                                    (const unsigned int*)mask, flags);

  dim3 ga(16, 32);
  if (ws_size >= need) {
    unsigned short* xb  = (unsigned short*)(ws + offXb);
    unsigned short* wbT = (unsigned short*)(ws + offWT);
    unsigned short* qb  = (unsigned short*)(ws + offQ);
    unsigned short* ekg = (unsigned short*)(ws + offEk);
    unsigned short* vmg = (unsigned short*)(ws + offVm);
    conv_x<<<(int)((size_t)M_ * DIM_ / 4 / 256), 256, 0, stream>>>(x, xb, flags);
    dim3 gt(E3_ / 64, DIM_ / 64);
    conv_wT<<<gt, 256, 0, stream>>>(w, wbT, flags);
    dim3 gg(E3_ / 128, M_ / 128);   // 12 x 128
    qkv_gemm_fused<<<gg, 256, 0, stream>>>(xb, wbT, bias, mask, flags, qb, ekg, vmg);
    kv_gemm<<<ga, 256, 0, stream>>>(ekg, vmg, kvbuf, denom);
    out_pass<<<ga, 256, 0, stream>>>(qb, kvbuf, denom, out);
  } else {
    kv_pass_fused <<<ga, 256, 0, stream>>>(x, w, bias, mask, flags, kvbuf, denom);
    out_pass_fused<<<ga, 256, 0, stream>>>(x, w, bias, flags, kvbuf, denom, out);
  }
}

// Round 8
// 221.065 us; speedup vs baseline: 13.9696x; 1.0650x over previous
//
#include <hip/hip_runtime.h>
#include <stdint.h>

#define B_   4
#define N_   4096
#define DIM_ 512
#define H_   8
#define DH_  64
#define E3_  1536
#define M_   (B_*N_)   // 16384

typedef __attribute__((ext_vector_type(8))) __bf16 bf16x8;
typedef __attribute__((ext_vector_type(8))) unsigned short ushort8;
typedef __attribute__((ext_vector_type(4))) float f32x4;

__device__ inline float bf2f(unsigned short u){ return __uint_as_float(((unsigned)u)<<16); }
__device__ inline unsigned short f2bf(float f){
  unsigned u = __float_as_uint(f);
  u += 0x7FFFu + ((u>>16)&1u);   // RNE
  return (unsigned short)(u>>16);
}

// async global->LDS, 16B per lane; lds dest must be wave-uniform base (+lane*16)
__device__ inline void gld_lds16(const void* g, void* l){
  __builtin_amdgcn_global_load_lds(
      (const __attribute__((address_space(1))) void*)g,
      (__attribute__((address_space(3))) void*)l, 16, 0, 0);
}

// ---------------- format detection ----------------
// flags[0]: x fp32?  flags[1]: W/bias fp32?  flags[2]: mask 0=i32,1=f32,2=bf16,3=u8
__global__ void detect_fmt(const unsigned int* __restrict__ xw,
                           const unsigned int* __restrict__ ww,
                           const unsigned int* __restrict__ mw,
                           int* __restrict__ flags)
{
  __shared__ int cnt[2];
  __shared__ int ok[3];
  if (threadIdx.x < 2) cnt[threadIdx.x] = 0;
  if (threadIdx.x < 3) ok[threadIdx.x] = 1;
  __syncthreads();
  int hx = 0, hw = 0;
  for (int i = threadIdx.x; i < 1024; i += 256) {
    if (((xw[i] >> 7) & 0xFFu) > 140u) hx++;
    if (((ww[i] >> 7) & 0xFFu) > 140u) hw++;
  }
  int okInt = 1, okF32 = 1, okBf = 1;
  for (int i = threadIdx.x; i < 4096; i += 256) {
    unsigned w = mw[i];
    if (w > 1u) okInt = 0;
    if (w != 0u && w != 0x3F800000u) okF32 = 0;
    unsigned short a = (unsigned short)(w & 0xFFFFu), b = (unsigned short)(w >> 16);
    if (!((a == 0 || a == 0x3F80u) && (b == 0 || b == 0x3F80u))) okBf = 0;
  }
  atomicAdd(&cnt[0], hx);
  atomicAdd(&cnt[1], hw);
  if (!okInt) atomicAnd(&ok[0], 0);
  if (!okF32) atomicAnd(&ok[1], 0);
  if (!okBf)  atomicAnd(&ok[2], 0);
  __syncthreads();
  if (threadIdx.x == 0) {
    flags[0] = cnt[0] > 64 ? 1 : 0;
    flags[1] = cnt[1] > 64 ? 1 : 0;
    flags[2] = ok[0] ? 0 : (ok[1] ? 1 : (ok[2] ? 2 : 3));
  }
}

__device__ inline bool mask_at(const void* m, int flag, int idx){
  if (flag == 0) return ((const int*)m)[idx] != 0;
  if (flag == 1) return ((const float*)m)[idx] != 0.f;
  if (flag == 2) return ((const unsigned short*)m)[idx] != 0;
  return ((const unsigned char*)m)[idx] != 0;
}
__device__ inline float gread(const void* p, int f32, size_t i){
  return f32 ? ((const float*)p)[i] : bf2f(((const unsigned short*)p)[i]);
}

// ---------------- convert x -> bf16 ----------------
__global__ __launch_bounds__(256)
void conv_x(const void* __restrict__ src, unsigned short* __restrict__ dst,
            const int* __restrict__ flags)
{
  const int f = flags[0];
  size_t i = ((size_t)blockIdx.x * 256 + threadIdx.x) * 4;
  #pragma unroll
  for (int j = 0; j < 4; ++j) dst[i + j] = f2bf(gread(src, f, i + j));
}

// ---------------- convert + transpose W: wbT[n][k] = W[k][n] ----------------
__global__ __launch_bounds__(256)
void conv_wT(const void* __restrict__ w, unsigned short* __restrict__ wbT,
             const int* __restrict__ flags)
{
  const int f = flags[1];
  __shared__ unsigned short ts[64][66];
  const int n0 = blockIdx.x * 64;
  const int k0 = blockIdx.y * 64;
  const int t = threadIdx.x;
  const int c = t & 63;
  #pragma unroll
  for (int p = 0; p < 16; ++p) {
    int r = (t >> 6) * 16 + p;
    ts[r][c] = f2bf(gread(w, f, (size_t)(k0 + r) * E3_ + n0 + c));
  }
  __syncthreads();
  #pragma unroll
  for (int p = 0; p < 16; ++p) {
    int nrow = (t >> 6) * 16 + p;
    wbT[(size_t)(n0 + nrow) * DIM_ + k0 + c] = ts[c][nrow];
  }
}

// ---------------- QKV GEMM (MFMA, global_load_lds staging) + fused epilogue ----------------
// 128x128 tile, BK=32, 4 waves x (4x4) 16x16x32 fragments.
// Col-blocks 0..3 = q -> qb; 4..7 = k -> ekg; 8..11 = v -> vmg.
// ekg/vmg layout: [bh][nn>>3][d][nn&7] bf16 (MFMA-frag-friendly).
__global__ __launch_bounds__(256)
void qkv_gemm_fused(const unsigned short* __restrict__ xb,   // M x 512 bf16
                    const unsigned short* __restrict__ wbT,  // 1536 x 512 bf16 (W^T)
                    const void* __restrict__ bias, const void* __restrict__ mask,
                    const int* __restrict__ flags,
                    unsigned short* __restrict__ qb,
                    unsigned short* __restrict__ ekg,
                    unsigned short* __restrict__ vmg)
{
  const int wf = flags[1], mf = flags[2];
  __shared__ alignas(16) unsigned short As[512 * 8];  // unit u=(koct*128+m): [m][koct*8..+7]
  __shared__ alignas(16) unsigned short Bs[512 * 8];
  const int t = threadIdx.x;
  const int lane = t & 63, wv = t >> 6;
  const int quad = lane >> 4, l15 = lane & 15;
  const int m0 = blockIdx.y * 128, n0 = blockIdx.x * 128;
  const int mw = (wv & 1) * 64, nw = (wv >> 1) * 64;

  f32x4 acc[4][4];
  #pragma unroll
  for (int i = 0; i < 4; ++i)
    #pragma unroll
    for (int j = 0; j < 4; ++j) acc[i][j] = (f32x4){0.f,0.f,0.f,0.f};

  // staging map: wave wv, shot s -> units [s*256+wv*64, +64); koct = u>>7 (wave-uniform),
  // m = (wv&1)*64 + lane
  const int mrow = (wv & 1) * 64 + lane;
  for (int kk = 0; kk < DIM_; kk += 32) {
    __syncthreads();   // prior frag reads done
    #pragma unroll
    for (int s = 0; s < 2; ++s) {
      const int u0 = s * 256 + wv * 64;
      const int koct = u0 >> 7;
      gld_lds16(xb  + (size_t)(m0 + mrow) * DIM_ + kk + koct * 8, &As[u0 * 8]);
      gld_lds16(wbT + (size_t)(n0 + mrow) * DIM_ + kk + koct * 8, &Bs[u0 * 8]);
    }
    __syncthreads();   // drains vmcnt before barrier
    ushort8 af[4], bfr[4];
    #pragma unroll
    for (int i = 0; i < 4; ++i) {
      af[i]  = *(const ushort8*)&As[(quad * 128 + mw + i * 16 + l15) * 8];
      bfr[i] = *(const ushort8*)&Bs[(quad * 128 + nw + i * 16 + l15) * 8];
    }
    #pragma unroll
    for (int i = 0; i < 4; ++i)
      #pragma unroll
      for (int j = 0; j < 4; ++j)
        acc[i][j] = __builtin_amdgcn_mfma_f32_16x16x32_bf16(
            __builtin_bit_cast(bf16x8, af[i]), __builtin_bit_cast(bf16x8, bfr[j]),
            acc[i][j], 0, 0, 0);
  }

  const int mode = blockIdx.x >> 2;   // 0=q, 1=k, 2=v (block-uniform)
  if (mode == 0) {
    #pragma unroll
    for (int j = 0; j < 4; ++j) {
      int col = n0 + nw + j * 16 + l15;
      float bv = gread(bias, wf, col);
      #pragma unroll
      for (int i = 0; i < 4; ++i)
        #pragma unroll
        for (int r = 0; r < 4; ++r) {
          int row = m0 + mw + i * 16 + quad * 4 + r;
          qb[(size_t)row * 512 + col] = f2bf(acc[i][j][r] + bv);
        }
    }
  } else {
    unsigned short* dstbuf = (mode == 1) ? ekg : vmg;
    float bj[4]; int hj[4], dj[4];
    #pragma unroll
    for (int j = 0; j < 4; ++j) {
      int col = n0 + nw + j * 16 + l15;
      bj[j] = gread(bias, wf, col);
      int rel = col - mode * 512;
      hj[j] = rel >> 6; dj[j] = rel & 63;
    }
    #pragma unroll
    for (int i = 0; i < 4; ++i)
      #pragma unroll
      for (int r = 0; r < 4; ++r) {
        int row = m0 + mw + i * 16 + quad * 4 + r;
        bool mk = mask_at(mask, mf, row);
        int b = row >> 12, nn = row & 4095;
        size_t base = (size_t)(nn >> 3) * 512 + (nn & 7);
        #pragma unroll
        for (int j = 0; j < 4; ++j) {
          float val = acc[i][j][r] + bj[j];
          val = (mode == 1) ? (mk ? __expf(val) : 0.f) : (mk ? val : 0.f);
          dstbuf[(size_t)(b * 8 + hj[j]) * 262144 + base + (size_t)dj[j] * 8] = f2bf(val);
        }
      }
  }
}

// ---------------- kv GEMM: per-block partial over 1024 tokens, NO atomics ----------------
__global__ __launch_bounds__(256)
void kv_gemm(const unsigned short* __restrict__ ekg,
             const unsigned short* __restrict__ vmg,
             float* __restrict__ kvpart, float* __restrict__ denpart)
{
  const int kc4 = blockIdx.x;  // 0..3 (1024-token super-chunk)
  const int bh  = blockIdx.y;  // 0..31
  const int t   = threadIdx.x;
  const int lane = t & 63, wv = t >> 6;
  const int quad = lane >> 4, l15 = lane & 15;
  __shared__ alignas(16) unsigned short ekS[16384];  // [ktl 0..31][d 0..63][8]
  __shared__ alignas(16) unsigned short vmS[16384];

  f32x4 acc[4];
  #pragma unroll
  for (int j = 0; j < 4; ++j) acc[j] = (f32x4){0.f,0.f,0.f,0.f};
  float dsum = 0.f;
  const int dden = t & 63, g0 = (t >> 6) * 8;

  for (int sc = 0; sc < 4; ++sc) {
    const size_t gbase = (size_t)bh * 262144 + (size_t)(kc4 * 4 + sc) * 16384;
    __syncthreads();
    #pragma unroll
    for (int i = 0; i < 8; ++i) {
      int u0 = i * 256 + wv * 64;          // wave-uniform LDS base, lane-contig global
      gld_lds16(&ekg[gbase + (size_t)(u0 + lane) * 8], &ekS[u0 * 8]);
      gld_lds16(&vmg[gbase + (size_t)(u0 + lane) * 8], &vmS[u0 * 8]);
    }
    __syncthreads();
    {  // denom partial: sum ek over staged tokens, per d
      #pragma unroll
      for (int kt = 0; kt < 8; ++kt) {
        ushort8 v = *(const ushort8*)&ekS[((g0 + kt) * 64 + dden) * 8];
        #pragma unroll
        for (int j = 0; j < 8; ++j) dsum += bf2f(v[j]);
      }
    }
    #pragma unroll 2
    for (int ks = 0; ks < 8; ++ks) {
      ushort8 af = *(const ushort8*)&ekS[((ks * 4 + quad) * 64 + wv * 16 + l15) * 8];
      #pragma unroll
      for (int jt = 0; jt < 4; ++jt) {
        ushort8 bf8 = *(const ushort8*)&vmS[((ks * 4 + quad) * 64 + jt * 16 + l15) * 8];
        acc[jt] = __builtin_amdgcn_mfma_f32_16x16x32_bf16(
            __builtin_bit_cast(bf16x8, af), __builtin_bit_cast(bf16x8, bf8),
            acc[jt], 0, 0, 0);
      }
    }
  }
  float* kvp = kvpart + (size_t)(kc4 * 32 + bh) * 4096;
  #pragma unroll
  for (int jt = 0; jt < 4; ++jt)
    #pragma unroll
    for (int r = 0; r < 4; ++r)
      kvp[(wv * 16 + quad * 4 + r) * 64 + jt * 16 + l15] = acc[jt][r];
  __syncthreads();
  float* red = (float*)ekS;
  red[t] = dsum;
  __syncthreads();
  if (t < 64)
    denpart[(kc4 * 32 + bh) * 64 + t] = red[t] + red[t + 64] + red[t + 128] + red[t + 192];
}

// ---------------- reduce partials -> normalized kv in bf16 B-frag layout ----------------
// kvnb[bh] unit (doct,e): holds kvn[doct*8+j][e], flat ((doct*64+e)*8+j)
__global__ __launch_bounds__(256)
void kv_reduce(const float* __restrict__ kvpart, const float* __restrict__ denpart,
               unsigned short* __restrict__ kvnb)
{
  const int bh = blockIdx.x;
  const int t  = threadIdx.x;
  __shared__ float den[64];
  if (t < 64) {
    float s = 0.f;
    #pragma unroll
    for (int c = 0; c < 4; ++c) s += denpart[(c * 32 + bh) * 64 + t];
    den[t] = s;
  }
  __syncthreads();
  const int d = t >> 2, e0 = (t & 3) * 16;
  const float inv = 1.f / den[d];
  #pragma unroll
  for (int j = 0; j < 16; ++j) {
    int e = e0 + j;
    float s = 0.f;
    #pragma unroll
    for (int c = 0; c < 4; ++c) s += kvpart[(size_t)(c * 32 + bh) * 4096 + d * 64 + e];
    kvnb[(size_t)bh * 4096 + ((size_t)(d >> 3) * 64 + e) * 8 + (d & 7)] = f2bf(s * inv);
  }
}

// ---------------- output: q-softmax + MFMA (16 tokens x 64 e per group) ----------------
__global__ __launch_bounds__(256)
void out_pass(const unsigned short* __restrict__ qb,
              const unsigned short* __restrict__ kvnb,
              float* __restrict__ out)
{
  const int chunk = blockIdx.x, bh = blockIdx.y;
  const int b = bh >> 3, h = bh & 7;
  const int t = threadIdx.x;
  const int lane = t & 63, wv = t >> 6;
  const int quad = lane >> 4, l15 = lane & 15;
  __shared__ alignas(16) unsigned short kvS[4096];   // [(doct*64+e)*8+j]
  __shared__ alignas(16) unsigned short qsmb[1024];  // [(koct*16+tok)*8+j]
  #pragma unroll
  for (int i = 0; i < 2; ++i)
    *(ushort8*)&kvS[(t + i * 256) * 8] =
        *(const ushort8*)&kvnb[(size_t)bh * 4096 + (size_t)(t + i * 256) * 8];

  const int tok = t >> 4, p = t & 15, d0 = p * 4;
  float qreg[4];
  {
    int row = b * N_ + chunk * 256 + tok;
    uint2 qw = *(const uint2*)(qb + (size_t)row * 512 + h * DH_ + d0);
    qreg[0] = bf2f((unsigned short)(qw.x & 0xffff));
    qreg[1] = bf2f((unsigned short)(qw.x >> 16));
    qreg[2] = bf2f((unsigned short)(qw.y & 0xffff));
    qreg[3] = bf2f((unsigned short)(qw.y >> 16));
  }
  for (int g = 0; g < 16; ++g) {
    const int row0 = b * N_ + chunk * 256 + g * 16;
    float mx = fmaxf(fmaxf(qreg[0], qreg[1]), fmaxf(qreg[2], qreg[3]));
    #pragma unroll
    for (int o = 1; o < 16; o <<= 1) mx = fmaxf(mx, __shfl_xor(mx, o, 16));
    float ex[4]; float s = 0.f;
    #pragma unroll
    for (int j = 0; j < 4; ++j) { ex[j] = __expf(qreg[j] - mx); s += ex[j]; }
    #pragma unroll
    for (int o = 1; o < 16; o <<= 1) s += __shfl_xor(s, o, 16);
    float inv = 1.f / s;
    __syncthreads();   // kvS ready (g=0) / prev MFMA's qsmb reads done
    #pragma unroll
    for (int j = 0; j < 4; ++j)
      qsmb[((size_t)((d0 + j) >> 3) * 16 + tok) * 8 + ((d0 + j) & 7)] = f2bf(ex[j] * inv);
    if (g < 15) {      // prefetch next group's q (overlaps barrier + MFMA)
      uint2 qw = *(const uint2*)(qb + (size_t)(row0 + 16 + tok) * 512 + h * DH_ + d0);
      qreg[0] = bf2f((unsigned short)(qw.x & 0xffff));
      qreg[1] = bf2f((unsigned short)(qw.x >> 16));
      qreg[2] = bf2f((unsigned short)(qw.y & 0xffff));
      qreg[3] = bf2f((unsigned short)(qw.y >> 16));
    }
    __syncthreads();
    f32x4 acc = (f32x4){0.f,0.f,0.f,0.f};
    #pragma unroll
    for (int s2 = 0; s2 < 2; ++s2) {
      int koct = s2 * 4 + quad;
      ushort8 a8 = *(const ushort8*)&qsmb[(koct * 16 + l15) * 8];
      ushort8 b8 = *(const ushort8*)&kvS[(koct * 64 + wv * 16 + l15) * 8];
      acc = __builtin_amdgcn_mfma_f32_16x16x32_bf16(
          __builtin_bit_cast(bf16x8, a8), __builtin_bit_cast(bf16x8, b8), acc, 0, 0, 0);
    }
    #pragma unroll
    for (int r = 0; r < 4; ++r)
      out[(size_t)(row0 + quad * 4 + r) * 512 + h * DH_ + wv * 16 + l15] = acc[r];
  }
}

// ================= round-5 fused fallback (only if ws too small) =================
__device__ inline void stage_x_f(float (*xa)[516], const void* x, int xf, int brow0, int t)
{
  if (xf) {
    const float* xp = (const float*)x;
    #pragma unroll
    for (int s = 0; s < 8; ++s) {
      int row = (t >> 7) + 2 * s, col = (t & 127) * 4;
      *(float4*)&xa[row][col] = *(const float4*)(xp + ((size_t)(brow0 + row)) * DIM_ + col);
    }
  } else {
    const unsigned short* xp = (const unsigned short*)x;
    #pragma unroll
    for (int s = 0; s < 8; ++s) {
      int row = (t >> 7) + 2 * s, col = (t & 127) * 4;
      const unsigned short* pp = xp + ((size_t)(brow0 + row)) * DIM_ + col;
      #pragma unroll
      for (int j = 0; j < 4; ++j) xa[row][col + j] = bf2f(pp[j]);
    }
  }
}

__global__ __launch_bounds__(256)
void kv_pass_fused(const void* __restrict__ x, const void* __restrict__ w,
                   const void* __restrict__ bias, const void* __restrict__ mask,
                   const int* __restrict__ flags,
                   float* __restrict__ kvbuf, float* __restrict__ denom)
{
  const int chunk = blockIdx.x, bh = blockIdx.y;
  const int b = bh >> 3, h = bh & 7;
  const int t = threadIdx.x;
  const int xf = flags[0], wf = flags[1], mf = flags[2];
  __shared__ float xa[16][516];
  __shared__ float Wb[64][130];
  float* ekb = &Wb[0][0];
  float* vvb = &Wb[0][0] + 16 * 65;
  const int tok = t >> 4, d0 = (t & 15) * 4;
  const int down = t >> 2, e0 = (t & 3) * 16;
  float acc[16];
  #pragma unroll
  for (int i = 0; i < 16; ++i) acc[i] = 0.f;
  float dsum = 0.f;
  for (int g = 0; g < 16; ++g) {
    const int n0 = chunk * 256 + g * 16;
    __syncthreads();
    stage_x_f(xa, x, xf, b * N_ + n0, t);
    float kreg[4] = {0,0,0,0}, vreg[4] = {0,0,0,0};
    for (int cc = 0; cc < 8; ++cc) {
      __syncthreads();
      {
        int c0 = (t >> 7) * 32, col = t & 127;
        int wc = (col < 64) ? (512 + h * DH_ + col) : (1024 + h * DH_ + (col - 64));
        #pragma unroll 8
        for (int j = 0; j < 32; ++j)
          Wb[c0 + j][col] = gread(w, wf, (size_t)(cc * 64 + c0 + j) * E3_ + wc);
      }
      __syncthreads();
      #pragma unroll 4
      for (int c = 0; c < 64; ++c) {
        float xv = xa[tok][cc * 64 + c];
        #pragma unroll
        for (int j = 0; j < 4; ++j) {
          kreg[j] += xv * Wb[c][d0 + j];
          vreg[j] += xv * Wb[c][64 + d0 + j];
        }
      }
    }
    bool mk = mask_at(mask, mf, b * N_ + n0 + tok);
    __syncthreads();
    #pragma unroll
    for (int j = 0; j < 4; ++j) {
      float kvl = kreg[j] + gread(bias, wf, 512  + h * DH_ + d0 + j);
      float vvl = vreg[j] + gread(bias, wf, 1024 + h * DH_ + d0 + j);
      ekb[tok * 65 + d0 + j] = mk ? __expf(kvl) : 0.f;
      vvb[tok * 65 + d0 + j] = mk ? vvl : 0.f;
    }
    __syncthreads();
    #pragma unroll 4
    for (int nn = 0; nn < 16; ++nn) {
      float ekd = ekb[nn * 65 + down];
      if (e0 == 0) dsum += ekd;
      #pragma unroll
      for (int i = 0; i < 16; ++i) acc[i] += ekd * vvb[nn * 65 + e0 + i];
    }
  }
  float* kvp = kvbuf + (size_t)bh * 4096 + down * 64 + e0;
  #pragma unroll
  for (int i = 0; i < 16; ++i) atomicAdd(&kvp[i], acc[i]);
  if (e0 == 0) atomicAdd(&denom[bh * 64 + down], dsum);
}

__global__ __launch_bounds__(256)
void out_pass_fused(const void* __restrict__ x, const void* __restrict__ w,
                    const void* __restrict__ bias, const int* __restrict__ flags,
                    const float* __restrict__ kvbuf, const float* __restrict__ denom,
                    float* __restrict__ out)
{
  const int chunk = blockIdx.x, bh = blockIdx.y;
  const int b = bh >> 3, h = bh & 7;
  const int t = threadIdx.x;
  const int xf = flags[0], wf = flags[1];
  __shared__ float xa[16][516];
  __shared__ float Wq[64][66];
  __shared__ float kvn[64][68];
  float* qsm = &Wq[0][0];
  for (int i = t; i < 4096; i += 256) {
    int d = i >> 6, e = i & 63;
    kvn[d][e] = kvbuf[(size_t)bh * 4096 + i] / denom[bh * 64 + d];
  }
  const int tok = t >> 4, p = t & 15, d0 = p * 4;
  for (int g = 0; g < 16; ++g) {
    const int n0 = chunk * 256 + g * 16;
    __syncthreads();
    stage_x_f(xa, x, xf, b * N_ + n0, t);
    float qreg[4] = {0,0,0,0};
    for (int cc = 0; cc < 8; ++cc) {
      __syncthreads();
      {
        int col = t & 63, c0 = (t >> 6) * 16;
        #pragma unroll 8
        for (int j = 0; j < 16; ++j)
          Wq[c0 + j][col] = gread(w, wf, (size_t)(cc * 64 + c0 + j) * E3_ + h * DH_ + col);
      }
      __syncthreads();
      #pragma unroll 4
      for (int c = 0; c < 64; ++c) {
        float xv = xa[tok][cc * 64 + c];
        #pragma unroll
        for (int j = 0; j < 4; ++j) qreg[j] += xv * Wq[c][d0 + j];
      }
    }
    #pragma unroll
    for (int j = 0; j < 4; ++j) qreg[j] += gread(bias, wf, h * DH_ + d0 + j);
    float mx = fmaxf(fmaxf(qreg[0], qreg[1]), fmaxf(qreg[2], qreg[3]));
    #pragma unroll
    for (int o = 1; o < 16; o <<= 1) mx = fmaxf(mx, __shfl_xor(mx, o, 16));
    float s = 0.f;
    #pragma unroll
    for (int j = 0; j < 4; ++j) { qreg[j] = __expf(qreg[j] - mx); s += qreg[j]; }
    #pragma unroll
    for (int o = 1; o < 16; o <<= 1) s += __shfl_xor(s, o, 16);
    float inv = 1.f / s;
    __syncthreads();
    #pragma unroll
    for (int j = 0; j < 4; ++j) qsm[tok * 65 + d0 + j] = qreg[j] * inv;
    __syncthreads();
    {
      int e0 = p * 4;
      float ov[4] = {0,0,0,0};
      #pragma unroll 4
      for (int d = 0; d < 64; ++d) {
        float qd = qsm[tok * 65 + d];
        #pragma unroll
        for (int j = 0; j < 4; ++j) ov[j] += qd * kvn[d][e0 + j];
      }
      size_t ob = ((size_t)(b * N_ + n0 + tok)) * DIM_ + h * DH_ + e0;
      #pragma unroll
      for (int j = 0; j < 4; ++j) out[ob + j] = ov[j];
    }
  }
}

extern "C" void kernel_launch(void* const* d_in, const int* in_sizes, int n_in,
                              void* d_out, int out_size, void* d_ws, size_t ws_size,
                              hipStream_t stream)
{
  const void* x    = d_in[0];
  const void* mask = d_in[1];
  const void* w    = d_in[2];
  const void* bias = d_in[3];
  float* out = (float*)d_out;

  char* ws = (char*)d_ws;
  // main-path layout (<= round-6 proven 69.2 MB bound)
  const size_t offFlg = 0;                                   // 4 KB slot
  const size_t offXb  = 4096;                                // 16.78 MB (dead after GEMM)
  const size_t offWT  = offXb + (size_t)M_ * DIM_ * 2;       // 1.57 MB
  const size_t offQ   = offWT + (size_t)E3_ * DIM_ * 2;      // 16.78 MB
  const size_t offEk  = offQ  + (size_t)M_ * DIM_ * 2;       // 16.78 MB
  const size_t offVm  = offEk + (size_t)M_ * DH_ * H_ * 2;   // 16.78 MB
  const size_t need   = offVm + (size_t)M_ * DH_ * H_ * 2;   // ~68.7 MB
  // aliased into dead xb region (after qkv_gemm_fused):
  const size_t offKvp = offXb;                               // 4*32*4096*4 = 2 MB
  const size_t offDnp = offXb + 2097152;                     // 32 KB
  const size_t offKvn = offXb + 2097152 + 32768;             // 256 KB

  int* flags = (int*)(ws + offFlg);
  detect_fmt<<<1, 256, 0, stream>>>((const unsigned int*)x, (const unsigned int*)w,
                                    (const unsigned int*)mask, flags);

  if (ws_size >= need) {
    unsigned short* xb  = (unsigned short*)(ws + offXb);
    unsigned short* wbT = (unsigned short*)(ws + offWT);
    unsigned short* qb  = (unsigned short*)(ws + offQ);
    unsigned short* ekg = (unsigned short*)(ws + offEk);
    unsigned short* vmg = (unsigned short*)(ws + offVm);
    float* kvpart = (float*)(ws + offKvp);
    float* denpart = (float*)(ws + offDnp);
    unsigned short* kvnb = (unsigned short*)(ws + offKvn);

    conv_x<<<(int)((size_t)M_ * DIM_ / 4 / 256), 256, 0, stream>>>(x, xb, flags);
    dim3 gt(E3_ / 64, DIM_ / 64);
    conv_wT<<<gt, 256, 0, stream>>>(w, wbT, flags);
    dim3 gg(E3_ / 128, M_ / 128);   // 12 x 128
    qkv_gemm_fused<<<gg, 256, 0, stream>>>(xb, wbT, bias, mask, flags, qb, ekg, vmg);
    dim3 gkv(4, 32);
    kv_gemm<<<gkv, 256, 0, stream>>>(ekg, vmg, kvpart, denpart);
    kv_reduce<<<32, 256, 0, stream>>>(kvpart, denpart, kvnb);
    dim3 ga(16, 32);
    out_pass<<<ga, 256, 0, stream>>>(qb, kvnb, out);
  } else {
    float* kvbuf = (float*)(ws + 4096);
    float* denom = (float*)(ws + 4096 + 32 * 4096 * 4);
    hipMemsetAsync(kvbuf, 0, 32 * 4096 * 4 + 32 * 64 * 4, stream);
    dim3 ga(16, 32);
    kv_pass_fused <<<ga, 256, 0, stream>>>(x, w, bias, mask, flags, kvbuf, denom);
    out_pass_fused<<<ga, 256, 0, stream>>>(x, w, bias, flags, kvbuf, denom, out);
  }
}

// Round 9
// 183.950 us; speedup vs baseline: 16.7883x; 1.2018x over previous
//
#include <hip/hip_runtime.h>
#include <stdint.h>

#define B_   4
#define N_   4096
#define DIM_ 512
#define H_   8
#define DH_  64
#define E3_  1536
#define M_   (B_*N_)   // 16384

typedef __attribute__((ext_vector_type(8))) __bf16 bf16x8;
typedef __attribute__((ext_vector_type(8))) unsigned short ushort8;
typedef __attribute__((ext_vector_type(4))) float f32x4;

__device__ inline float bf2f(unsigned short u){ return __uint_as_float(((unsigned)u)<<16); }
__device__ inline unsigned short f2bf(float f){
  unsigned u = __float_as_uint(f);
  u += 0x7FFFu + ((u>>16)&1u);   // RNE
  return (unsigned short)(u>>16);
}

// async global->LDS, 16B per lane; lds dest = wave-uniform base + lane*16
__device__ inline void gld_lds16(const void* g, void* l){
  __builtin_amdgcn_global_load_lds(
      (const __attribute__((address_space(1))) void*)g,
      (__attribute__((address_space(3))) void*)l, 16, 0, 0);
}

// ---------------- format detection ----------------
// flags[0]: x fp32?  flags[1]: W/bias fp32?  flags[2]: mask 0=i32,1=f32,2=bf16,3=u8
__global__ void detect_fmt(const unsigned int* __restrict__ xw,
                           const unsigned int* __restrict__ ww,
                           const unsigned int* __restrict__ mw,
                           int* __restrict__ flags)
{
  __shared__ int cnt[2];
  __shared__ int ok[3];
  if (threadIdx.x < 2) cnt[threadIdx.x] = 0;
  if (threadIdx.x < 3) ok[threadIdx.x] = 1;
  __syncthreads();
  int hx = 0, hw = 0;
  for (int i = threadIdx.x; i < 1024; i += 256) {
    if (((xw[i] >> 7) & 0xFFu) > 140u) hx++;
    if (((ww[i] >> 7) & 0xFFu) > 140u) hw++;
  }
  int okInt = 1, okF32 = 1, okBf = 1;
  for (int i = threadIdx.x; i < 4096; i += 256) {
    unsigned w = mw[i];
    if (w > 1u) okInt = 0;
    if (w != 0u && w != 0x3F800000u) okF32 = 0;
    unsigned short a = (unsigned short)(w & 0xFFFFu), b = (unsigned short)(w >> 16);
    if (!((a == 0 || a == 0x3F80u) && (b == 0 || b == 0x3F80u))) okBf = 0;
  }
  atomicAdd(&cnt[0], hx);
  atomicAdd(&cnt[1], hw);
  if (!okInt) atomicAnd(&ok[0], 0);
  if (!okF32) atomicAnd(&ok[1], 0);
  if (!okBf)  atomicAnd(&ok[2], 0);
  __syncthreads();
  if (threadIdx.x == 0) {
    flags[0] = cnt[0] > 64 ? 1 : 0;
    flags[1] = cnt[1] > 64 ? 1 : 0;
    flags[2] = ok[0] ? 0 : (ok[1] ? 1 : (ok[2] ? 2 : 3));
  }
}

__device__ inline bool mask_at(const void* m, int flag, int idx){
  if (flag == 0) return ((const int*)m)[idx] != 0;
  if (flag == 1) return ((const float*)m)[idx] != 0.f;
  if (flag == 2) return ((const unsigned short*)m)[idx] != 0;
  return ((const unsigned char*)m)[idx] != 0;
}
__device__ inline float gread(const void* p, int f32, size_t i){
  return f32 ? ((const float*)p)[i] : bf2f(((const unsigned short*)p)[i]);
}

// ---------------- pack x into per-tile LDS images ----------------
// xq[((R*16 + kk)*512 + u)*8 + j], u = koct*128 + mlocal, covers
// x[R*128+mlocal][kk*32 + koct*8 + j] as bf16. Writes fully coalesced.
__global__ __launch_bounds__(256)
void pack_x(const void* __restrict__ x, unsigned short* __restrict__ xq,
            const int* __restrict__ flags)
{
  const int f = flags[0];
  const int g = blockIdx.x * 256 + threadIdx.x;   // unit id, 0..1048575
  const int R = g >> 13, rem = g & 8191;
  const int kk = rem >> 9, u = rem & 511;
  const int m = R * 128 + (u & 127);
  const int k0 = kk * 32 + (u >> 7) * 8;
  ushort8 v;
  if (f) {
    const float* xp = (const float*)x + (size_t)m * DIM_ + k0;
    float4 a = *(const float4*)xp, b = *(const float4*)(xp + 4);
    v[0]=f2bf(a.x); v[1]=f2bf(a.y); v[2]=f2bf(a.z); v[3]=f2bf(a.w);
    v[4]=f2bf(b.x); v[5]=f2bf(b.y); v[6]=f2bf(b.z); v[7]=f2bf(b.w);
  } else {
    v = *(const ushort8*)((const unsigned short*)x + (size_t)m * DIM_ + k0);
  }
  *(ushort8*)&xq[(size_t)g * 8] = v;
}

// ---------------- pack W into per-tile LDS images (with transpose) ----------------
// wq[((C*16 + kk)*512 + u)*8 + j], u = koct*128 + nlocal, covers
// W[kk*32 + koct*8 + j][C*128 + nlocal] as bf16.
__global__ __launch_bounds__(256)
void pack_w(const void* __restrict__ w, unsigned short* __restrict__ wq,
            const int* __restrict__ flags)
{
  const int f = flags[1];
  const int g = blockIdx.x * 256 + threadIdx.x;   // 0..98303
  const int C = g >> 13, rem = g & 8191;
  const int kk = rem >> 9, u = rem & 511;
  const int n = C * 128 + (u & 127);
  const int k0 = kk * 32 + (u >> 7) * 8;
  ushort8 v;
  #pragma unroll
  for (int j = 0; j < 8; ++j) v[j] = f2bf(gread(w, f, (size_t)(k0 + j) * E3_ + n));
  *(ushort8*)&wq[(size_t)g * 8] = v;
}

// ---------------- QKV GEMM (MFMA, coalesced global_load_lds) + fused epilogue ----------------
// 128x128 tile, BK=32, 4 waves x (4x4) 16x16x32 fragments.
// Col-blocks 0..3 = q -> qb; 4..7 = k -> ekg; 8..11 = v -> vmg.
// ekg/vmg layout: [bh][nn>>3][d][nn&7] bf16 (MFMA-frag-friendly).
__global__ __launch_bounds__(256)
void qkv_gemm_fused(const unsigned short* __restrict__ xq,   // packed tile images
                    const unsigned short* __restrict__ wq,   // packed tile images
                    const void* __restrict__ bias, const void* __restrict__ mask,
                    const int* __restrict__ flags,
                    unsigned short* __restrict__ qb,
                    unsigned short* __restrict__ ekg,
                    unsigned short* __restrict__ vmg)
{
  const int wf = flags[1], mf = flags[2];
  __shared__ alignas(16) unsigned short As[512 * 8];  // unit u=(koct*128+m)
  __shared__ alignas(16) unsigned short Bs[512 * 8];
  const int t = threadIdx.x;
  const int lane = t & 63, wv = t >> 6;
  const int quad = lane >> 4, l15 = lane & 15;
  const int m0 = blockIdx.y * 128, n0 = blockIdx.x * 128;
  const int mw = (wv & 1) * 64, nw = (wv >> 1) * 64;

  f32x4 acc[4][4];
  #pragma unroll
  for (int i = 0; i < 4; ++i)
    #pragma unroll
    for (int j = 0; j < 4; ++j) acc[i][j] = (f32x4){0.f,0.f,0.f,0.f};

  for (int kk = 0; kk < 16; ++kk) {
    const unsigned short* aim = xq + ((size_t)(blockIdx.y * 16 + kk) * 512) * 8;
    const unsigned short* bim = wq + ((size_t)(blockIdx.x * 16 + kk) * 512) * 8;
    __syncthreads();   // prior frag reads done
    #pragma unroll
    for (int s = 0; s < 2; ++s) {
      const int u0 = s * 256 + wv * 64;   // wave-uniform LDS base; lane-contiguous global
      gld_lds16(aim + (size_t)(u0 + lane) * 8, &As[u0 * 8]);
      gld_lds16(bim + (size_t)(u0 + lane) * 8, &Bs[u0 * 8]);
    }
    __syncthreads();   // drains vmcnt
    ushort8 af[4], bfr[4];
    #pragma unroll
    for (int i = 0; i < 4; ++i) {
      af[i]  = *(const ushort8*)&As[(quad * 128 + mw + i * 16 + l15) * 8];
      bfr[i] = *(const ushort8*)&Bs[(quad * 128 + nw + i * 16 + l15) * 8];
    }
    #pragma unroll
    for (int i = 0; i < 4; ++i)
      #pragma unroll
      for (int j = 0; j < 4; ++j)
        acc[i][j] = __builtin_amdgcn_mfma_f32_16x16x32_bf16(
            __builtin_bit_cast(bf16x8, af[i]), __builtin_bit_cast(bf16x8, bfr[j]),
            acc[i][j], 0, 0, 0);
  }

  const int mode = blockIdx.x >> 2;   // 0=q, 1=k, 2=v (block-uniform)
  if (mode == 0) {
    #pragma unroll
    for (int j = 0; j < 4; ++j) {
      int col = n0 + nw + j * 16 + l15;
      float bv = gread(bias, wf, col);
      #pragma unroll
      for (int i = 0; i < 4; ++i)
        #pragma unroll
        for (int r = 0; r < 4; ++r) {
          int row = m0 + mw + i * 16 + quad * 4 + r;
          qb[(size_t)row * 512 + col] = f2bf(acc[i][j][r] + bv);
        }
    }
  } else {
    unsigned short* dstbuf = (mode == 1) ? ekg : vmg;
    float bj[4]; int hj[4], dj[4];
    #pragma unroll
    for (int j = 0; j < 4; ++j) {
      int col = n0 + nw + j * 16 + l15;
      bj[j] = gread(bias, wf, col);
      int rel = col - mode * 512;
      hj[j] = rel >> 6; dj[j] = rel & 63;
    }
    #pragma unroll
    for (int i = 0; i < 4; ++i)
      #pragma unroll
      for (int r = 0; r < 4; ++r) {
        int row = m0 + mw + i * 16 + quad * 4 + r;
        bool mk = mask_at(mask, mf, row);
        int b = row >> 12, nn = row & 4095;
        size_t base = (size_t)(nn >> 3) * 512 + (nn & 7);
        #pragma unroll
        for (int j = 0; j < 4; ++j) {
          float val = acc[i][j][r] + bj[j];
          val = (mode == 1) ? (mk ? __expf(val) : 0.f) : (mk ? val : 0.f);
          dstbuf[(size_t)(b * 8 + hj[j]) * 262144 + base + (size_t)dj[j] * 8] = f2bf(val);
        }
      }
  }
}

// ---------------- kv GEMM: per-block partial over 512 tokens, NO atomics ----------------
__global__ __launch_bounds__(256)
void kv_gemm(const unsigned short* __restrict__ ekg,
             const unsigned short* __restrict__ vmg,
             float* __restrict__ kvpart, float* __restrict__ denpart)
{
  const int kc8 = blockIdx.x;  // 0..7 (512-token super-chunk)
  const int bh  = blockIdx.y;  // 0..31
  const int t   = threadIdx.x;
  const int lane = t & 63, wv = t >> 6;
  const int quad = lane >> 4, l15 = lane & 15;
  __shared__ alignas(16) unsigned short ekS[16384];  // [ktl 0..31][d 0..63][8]
  __shared__ alignas(16) unsigned short vmS[16384];

  f32x4 acc[4];
  #pragma unroll
  for (int j = 0; j < 4; ++j) acc[j] = (f32x4){0.f,0.f,0.f,0.f};
  float dsum = 0.f;
  const int dden = t & 63, g0 = (t >> 6) * 8;

  for (int sc = 0; sc < 2; ++sc) {
    const size_t gbase = (size_t)bh * 262144 + (size_t)(kc8 * 2 + sc) * 16384;
    __syncthreads();
    #pragma unroll
    for (int i = 0; i < 8; ++i) {
      int u0 = i * 256 + wv * 64;          // wave-uniform LDS base, lane-contig global
      gld_lds16(&ekg[gbase + (size_t)(u0 + lane) * 8], &ekS[u0 * 8]);
      gld_lds16(&vmg[gbase + (size_t)(u0 + lane) * 8], &vmS[u0 * 8]);
    }
    __syncthreads();
    {  // denom partial: sum ek over staged tokens, per d
      #pragma unroll
      for (int kt = 0; kt < 8; ++kt) {
        ushort8 v = *(const ushort8*)&ekS[((g0 + kt) * 64 + dden) * 8];
        #pragma unroll
        for (int j = 0; j < 8; ++j) dsum += bf2f(v[j]);
      }
    }
    #pragma unroll 2
    for (int ks = 0; ks < 8; ++ks) {
      ushort8 af = *(const ushort8*)&ekS[((ks * 4 + quad) * 64 + wv * 16 + l15) * 8];
      #pragma unroll
      for (int jt = 0; jt < 4; ++jt) {
        ushort8 bf8 = *(const ushort8*)&vmS[((ks * 4 + quad) * 64 + jt * 16 + l15) * 8];
        acc[jt] = __builtin_amdgcn_mfma_f32_16x16x32_bf16(
            __builtin_bit_cast(bf16x8, af), __builtin_bit_cast(bf16x8, bf8),
            acc[jt], 0, 0, 0);
      }
    }
  }
  float* kvp = kvpart + (size_t)(kc8 * 32 + bh) * 4096;
  #pragma unroll
  for (int jt = 0; jt < 4; ++jt)
    #pragma unroll
    for (int r = 0; r < 4; ++r)
      kvp[(wv * 16 + quad * 4 + r) * 64 + jt * 16 + l15] = acc[jt][r];
  __syncthreads();
  float* red = (float*)ekS;
  red[t] = dsum;
  __syncthreads();
  if (t < 64)
    denpart[(kc8 * 32 + bh) * 64 + t] = red[t] + red[t + 64] + red[t + 128] + red[t + 192];
}

// ---------------- reduce partials -> normalized kv in bf16 B-frag layout ----------------
// kvnb[bh] unit (doct,e): holds kvn[doct*8+j][e], flat ((doct*64+e)*8+j)
__global__ __launch_bounds__(256)
void kv_reduce(const float* __restrict__ kvpart, const float* __restrict__ denpart,
               unsigned short* __restrict__ kvnb)
{
  const int bh = blockIdx.x;
  const int t  = threadIdx.x;
  __shared__ float den[64];
  if (t < 64) {
    float s = 0.f;
    #pragma unroll
    for (int c = 0; c < 8; ++c) s += denpart[(c * 32 + bh) * 64 + t];
    den[t] = s;
  }
  __syncthreads();
  const int d = t >> 2, e0 = (t & 3) * 16;
  const float inv = 1.f / den[d];
  #pragma unroll
  for (int j = 0; j < 16; ++j) {
    int e = e0 + j;
    float s = 0.f;
    #pragma unroll
    for (int c = 0; c < 8; ++c) s += kvpart[(size_t)(c * 32 + bh) * 4096 + d * 64 + e];
    kvnb[(size_t)bh * 4096 + ((size_t)(d >> 3) * 64 + e) * 8 + (d & 7)] = f2bf(s * inv);
  }
}

// ---------------- output: q-softmax + MFMA (16 tokens x 64 e per group) ----------------
__global__ __launch_bounds__(256)
void out_pass(const unsigned short* __restrict__ qb,
              const unsigned short* __restrict__ kvnb,
              float* __restrict__ out)
{
  const int chunk = blockIdx.x, bh = blockIdx.y;
  const int b = bh >> 3, h = bh & 7;
  const int t = threadIdx.x;
  const int lane = t & 63, wv = t >> 6;
  const int quad = lane >> 4, l15 = lane & 15;
  __shared__ alignas(16) unsigned short kvS[4096];   // [(doct*64+e)*8+j]
  __shared__ alignas(16) unsigned short qsmb[1024];  // [(koct*16+tok)*8+j]
  #pragma unroll
  for (int i = 0; i < 2; ++i)
    *(ushort8*)&kvS[(t + i * 256) * 8] =
        *(const ushort8*)&kvnb[(size_t)bh * 4096 + (size_t)(t + i * 256) * 8];

  const int tok = t >> 4, p = t & 15, d0 = p * 4;
  float qreg[4];
  {
    int row = b * N_ + chunk * 256 + tok;
    uint2 qw = *(const uint2*)(qb + (size_t)row * 512 + h * DH_ + d0);
    qreg[0] = bf2f((unsigned short)(qw.x & 0xffff));
    qreg[1] = bf2f((unsigned short)(qw.x >> 16));
    qreg[2] = bf2f((unsigned short)(qw.y & 0xffff));
    qreg[3] = bf2f((unsigned short)(qw.y >> 16));
  }
  for (int g = 0; g < 16; ++g) {
    const int row0 = b * N_ + chunk * 256 + g * 16;
    float mx = fmaxf(fmaxf(qreg[0], qreg[1]), fmaxf(qreg[2], qreg[3]));
    #pragma unroll
    for (int o = 1; o < 16; o <<= 1) mx = fmaxf(mx, __shfl_xor(mx, o, 16));
    float ex[4]; float s = 0.f;
    #pragma unroll
    for (int j = 0; j < 4; ++j) { ex[j] = __expf(qreg[j] - mx); s += ex[j]; }
    #pragma unroll
    for (int o = 1; o < 16; o <<= 1) s += __shfl_xor(s, o, 16);
    float inv = 1.f / s;
    __syncthreads();   // kvS ready (g=0) / prev MFMA's qsmb reads done
    #pragma unroll
    for (int j = 0; j < 4; ++j)
      qsmb[((size_t)((d0 + j) >> 3) * 16 + tok) * 8 + ((d0 + j) & 7)] = f2bf(ex[j] * inv);
    if (g < 15) {      // prefetch next group's q (overlaps barrier + MFMA)
      uint2 qw = *(const uint2*)(qb + (size_t)(row0 + 16 + tok) * 512 + h * DH_ + d0);
      qreg[0] = bf2f((unsigned short)(qw.x & 0xffff));
      qreg[1] = bf2f((unsigned short)(qw.x >> 16));
      qreg[2] = bf2f((unsigned short)(qw.y & 0xffff));
      qreg[3] = bf2f((unsigned short)(qw.y >> 16));
    }
    __syncthreads();
    f32x4 acc = (f32x4){0.f,0.f,0.f,0.f};
    #pragma unroll
    for (int s2 = 0; s2 < 2; ++s2) {
      int koct = s2 * 4 + quad;
      ushort8 a8 = *(const ushort8*)&qsmb[(koct * 16 + l15) * 8];
      ushort8 b8 = *(const ushort8*)&kvS[(koct * 64 + wv * 16 + l15) * 8];
      acc = __builtin_amdgcn_mfma_f32_16x16x32_bf16(
          __builtin_bit_cast(bf16x8, a8), __builtin_bit_cast(bf16x8, b8), acc, 0, 0, 0);
    }
    #pragma unroll
    for (int r = 0; r < 4; ++r)
      out[(size_t)(row0 + quad * 4 + r) * 512 + h * DH_ + wv * 16 + l15] = acc[r];
  }
}

// ================= round-5 fused fallback (only if ws too small) =================
__device__ inline void stage_x_f(float (*xa)[516], const void* x, int xf, int brow0, int t)
{
  if (xf) {
    const float* xp = (const float*)x;
    #pragma unroll
    for (int s = 0; s < 8; ++s) {
      int row = (t >> 7) + 2 * s, col = (t & 127) * 4;
      *(float4*)&xa[row][col] = *(const float4*)(xp + ((size_t)(brow0 + row)) * DIM_ + col);
    }
  } else {
    const unsigned short* xp = (const unsigned short*)x;
    #pragma unroll
    for (int s = 0; s < 8; ++s) {
      int row = (t >> 7) + 2 * s, col = (t & 127) * 4;
      const unsigned short* pp = xp + ((size_t)(brow0 + row)) * DIM_ + col;
      #pragma unroll
      for (int j = 0; j < 4; ++j) xa[row][col + j] = bf2f(pp[j]);
    }
  }
}

__global__ __launch_bounds__(256)
void kv_pass_fused(const void* __restrict__ x, const void* __restrict__ w,
                   const void* __restrict__ bias, const void* __restrict__ mask,
                   const int* __restrict__ flags,
                   float* __restrict__ kvbuf, float* __restrict__ denom)
{
  const int chunk = blockIdx.x, bh = blockIdx.y;
  const int b = bh >> 3, h = bh & 7;
  const int t = threadIdx.x;
  const int xf = flags[0], wf = flags[1], mf = flags[2];
  __shared__ float xa[16][516];
  __shared__ float Wb[64][130];
  float* ekb = &Wb[0][0];
  float* vvb = &Wb[0][0] + 16 * 65;
  const int tok = t >> 4, d0 = (t & 15) * 4;
  const int down = t >> 2, e0 = (t & 3) * 16;
  float acc[16];
  #pragma unroll
  for (int i = 0; i < 16; ++i) acc[i] = 0.f;
  float dsum = 0.f;
  for (int g = 0; g < 16; ++g) {
    const int n0 = chunk * 256 + g * 16;
    __syncthreads();
    stage_x_f(xa, x, xf, b * N_ + n0, t);
    float kreg[4] = {0,0,0,0}, vreg[4] = {0,0,0,0};
    for (int cc = 0; cc < 8; ++cc) {
      __syncthreads();
      {
        int c0 = (t >> 7) * 32, col = t & 127;
        int wc = (col < 64) ? (512 + h * DH_ + col) : (1024 + h * DH_ + (col - 64));
        #pragma unroll 8
        for (int j = 0; j < 32; ++j)
          Wb[c0 + j][col] = gread(w, wf, (size_t)(cc * 64 + c0 + j) * E3_ + wc);
      }
      __syncthreads();
      #pragma unroll 4
      for (int c = 0; c < 64; ++c) {
        float xv = xa[tok][cc * 64 + c];
        #pragma unroll
        for (int j = 0; j < 4; ++j) {
          kreg[j] += xv * Wb[c][d0 + j];
          vreg[j] += xv * Wb[c][64 + d0 + j];
        }
      }
    }
    bool mk = mask_at(mask, mf, b * N_ + n0 + tok);
    __syncthreads();
    #pragma unroll
    for (int j = 0; j < 4; ++j) {
      float kvl = kreg[j] + gread(bias, wf, 512  + h * DH_ + d0 + j);
      float vvl = vreg[j] + gread(bias, wf, 1024 + h * DH_ + d0 + j);
      ekb[tok * 65 + d0 + j] = mk ? __expf(kvl) : 0.f;
      vvb[tok * 65 + d0 + j] = mk ? vvl : 0.f;
    }
    __syncthreads();
    #pragma unroll 4
    for (int nn = 0; nn < 16; ++nn) {
      float ekd = ekb[nn * 65 + down];
      if (e0 == 0) dsum += ekd;
      #pragma unroll
      for (int i = 0; i < 16; ++i) acc[i] += ekd * vvb[nn * 65 + e0 + i];
    }
  }
  float* kvp = kvbuf + (size_t)bh * 4096 + down * 64 + e0;
  #pragma unroll
  for (int i = 0; i < 16; ++i) atomicAdd(&kvp[i], acc[i]);
  if (e0 == 0) atomicAdd(&denom[bh * 64 + down], dsum);
}

__global__ __launch_bounds__(256)
void out_pass_fused(const void* __restrict__ x, const void* __restrict__ w,
                    const void* __restrict__ bias, const int* __restrict__ flags,
                    const float* __restrict__ kvbuf, const float* __restrict__ denom,
                    float* __restrict__ out)
{
  const int chunk = blockIdx.x, bh = blockIdx.y;
  const int b = bh >> 3, h = bh & 7;
  const int t = threadIdx.x;
  const int xf = flags[0], wf = flags[1];
  __shared__ float xa[16][516];
  __shared__ float Wq[64][66];
  __shared__ float kvn[64][68];
  float* qsm = &Wq[0][0];
  for (int i = t; i < 4096; i += 256) {
    int d = i >> 6, e = i & 63;
    kvn[d][e] = kvbuf[(size_t)bh * 4096 + i] / denom[bh * 64 + d];
  }
  const int tok = t >> 4, p = t & 15, d0 = p * 4;
  for (int g = 0; g < 16; ++g) {
    const int n0 = chunk * 256 + g * 16;
    __syncthreads();
    stage_x_f(xa, x, xf, b * N_ + n0, t);
    float qreg[4] = {0,0,0,0};
    for (int cc = 0; cc < 8; ++cc) {
      __syncthreads();
      {
        int col = t & 63, c0 = (t >> 6) * 16;
        #pragma unroll 8
        for (int j = 0; j < 16; ++j)
          Wq[c0 + j][col] = gread(w, wf, (size_t)(cc * 64 + c0 + j) * E3_ + h * DH_ + col);
      }
      __syncthreads();
      #pragma unroll 4
      for (int c = 0; c < 64; ++c) {
        float xv = xa[tok][cc * 64 + c];
        #pragma unroll
        for (int j = 0; j < 4; ++j) qreg[j] += xv * Wq[c][d0 + j];
      }
    }
    #pragma unroll
    for (int j = 0; j < 4; ++j) qreg[j] += gread(bias, wf, h * DH_ + d0 + j);
    float mx = fmaxf(fmaxf(qreg[0], qreg[1]), fmaxf(qreg[2], qreg[3]));
    #pragma unroll
    for (int o = 1; o < 16; o <<= 1) mx = fmaxf(mx, __shfl_xor(mx, o, 16));
    float s = 0.f;
    #pragma unroll
    for (int j = 0; j < 4; ++j) { qreg[j] = __expf(qreg[j] - mx); s += qreg[j]; }
    #pragma unroll
    for (int o = 1; o < 16; o <<= 1) s += __shfl_xor(s, o, 16);
    float inv = 1.f / s;
    __syncthreads();
    #pragma unroll
    for (int j = 0; j < 4; ++j) qsm[tok * 65 + d0 + j] = qreg[j] * inv;
    __syncthreads();
    {
      int e0 = p * 4;
      float ov[4] = {0,0,0,0};
      #pragma unroll 4
      for (int d = 0; d < 64; ++d) {
        float qd = qsm[tok * 65 + d];
        #pragma unroll
        for (int j = 0; j < 4; ++j) ov[j] += qd * kvn[d][e0 + j];
      }
      size_t ob = ((size_t)(b * N_ + n0 + tok)) * DIM_ + h * DH_ + e0;
      #pragma unroll
      for (int j = 0; j < 4; ++j) out[ob + j] = ov[j];
    }
  }
}

extern "C" void kernel_launch(void* const* d_in, const int* in_sizes, int n_in,
                              void* d_out, int out_size, void* d_ws, size_t ws_size,
                              hipStream_t stream)
{
  const void* x    = d_in[0];
  const void* mask = d_in[1];
  const void* w    = d_in[2];
  const void* bias = d_in[3];
  float* out = (float*)d_out;

  char* ws = (char*)d_ws;
  // main-path layout (== round-8 proven bound, ~68.7 MB)
  const size_t offFlg = 0;                                   // 4 KB slot
  const size_t offXq  = 4096;                                // 16.78 MB (dead after GEMM)
  const size_t offWq  = offXq + (size_t)M_ * DIM_ * 2;       // 1.57 MB
  const size_t offQ   = offWq + (size_t)E3_ * DIM_ * 2;      // 16.78 MB
  const size_t offEk  = offQ  + (size_t)M_ * DIM_ * 2;       // 16.78 MB
  const size_t offVm  = offEk + (size_t)M_ * DH_ * H_ * 2;   // 16.78 MB
  const size_t need   = offVm + (size_t)M_ * DH_ * H_ * 2;
  // aliased into dead xq region (after qkv_gemm_fused):
  const size_t offKvp = offXq;                               // 8*32*4096*4 = 4 MB
  const size_t offDnp = offXq + 4194304;                     // 64 KB
  const size_t offKvn = offXq + 4194304 + 65536;             // 256 KB

  int* flags = (int*)(ws + offFlg);
  detect_fmt<<<1, 256, 0, stream>>>((const unsigned int*)x, (const unsigned int*)w,
                                    (const unsigned int*)mask, flags);

  if (ws_size >= need) {
    unsigned short* xq  = (unsigned short*)(ws + offXq);
    unsigned short* wq  = (unsigned short*)(ws + offWq);
    unsigned short* qb  = (unsigned short*)(ws + offQ);
    unsigned short* ekg = (unsigned short*)(ws + offEk);
    unsigned short* vmg = (unsigned short*)(ws + offVm);
    float* kvpart = (float*)(ws + offKvp);
    float* denpart = (float*)(ws + offDnp);
    unsigned short* kvnb = (unsigned short*)(ws + offKvn);

    pack_x<<<4096, 256, 0, stream>>>(x, xq, flags);
    pack_w<<<384, 256, 0, stream>>>(w, wq, flags);
    dim3 gg(E3_ / 128, M_ / 128);   // 12 x 128
    qkv_gemm_fused<<<gg, 256, 0, stream>>>(xq, wq, bias, mask, flags, qb, ekg, vmg);
    dim3 gkv(8, 32);
    kv_gemm<<<gkv, 256, 0, stream>>>(ekg, vmg, kvpart, denpart);
    kv_reduce<<<32, 256, 0, stream>>>(kvpart, denpart, kvnb);
    dim3 ga(16, 32);
    out_pass<<<ga, 256, 0, stream>>>(qb, kvnb, out);
  } else {
    float* kvbuf = (float*)(ws + 4096);
    float* denom = (float*)(ws + 4096 + 32 * 4096 * 4);
    hipMemsetAsync(kvbuf, 0, 32 * 4096 * 4 + 32 * 64 * 4, stream);
    dim3 ga(16, 32);
    kv_pass_fused <<<ga, 256, 0, stream>>>(x, w, bias, mask, flags, kvbuf, denom);
    out_pass_fused<<<ga, 256, 0, stream>>>(x, w, bias, flags, kvbuf, denom, out);
  }
}